// Round 4
// baseline (220.076 us; speedup 1.0000x reference)
//
#include <hip/hip_runtime.h>
#include <hip/hip_bf16.h>
#include <stdint.h>

typedef __bf16 bf16;
typedef __bf16 bf16x4 __attribute__((ext_vector_type(4)));
typedef __bf16 bf16x8 __attribute__((ext_vector_type(8)));
typedef float f32x4 __attribute__((ext_vector_type(4)));
typedef float f32x16 __attribute__((ext_vector_type(16)));

#define GLDS16(g, l) __builtin_amdgcn_global_load_lds( \
    (const __attribute__((address_space(1))) void*)(g), \
    (__attribute__((address_space(3))) void*)(l), 16, 0, 0)

static constexpr int S = 2048;

// ---------------- fused f32 -> bf16 convert: x + 4 weights, 1 launch --------
__global__ __launch_bounds__(256) void cvt_all(const float* __restrict__ x,
                                               const float* __restrict__ wq,
                                               const float* __restrict__ wk,
                                               const float* __restrict__ wv,
                                               const float* __restrict__ wo,
                                               bf16* __restrict__ xb,
                                               bf16* __restrict__ wqkvb,
                                               bf16* __restrict__ wob) {
  const int bid = blockIdx.x;
  const float* src;
  bf16* dst;
  int i;
  if (bid < 4096) {            // x: 1,048,576 groups of 8
    src = x; dst = xb; i = bid * 256 + threadIdx.x;
  } else {                     // weights: 131,072 groups each
    int w = (bid - 4096) >> 9;
    i = ((bid - 4096) & 511) * 256 + threadIdx.x;
    src = (w == 0) ? wq : (w == 1) ? wk : (w == 2) ? wv : wo;
    dst = (w == 3) ? wob : wqkvb + (size_t)w * 1048576;
  }
  const float4* p = (const float4*)src + (size_t)i * 2;
  float4 a = p[0], b = p[1];
  bf16x8 o;
  o[0] = (bf16)a.x; o[1] = (bf16)a.y; o[2] = (bf16)a.z; o[3] = (bf16)a.w;
  o[4] = (bf16)b.x; o[5] = (bf16)b.y; o[6] = (bf16)b.z; o[7] = (bf16)b.w;
  *((bf16x8*)dst + i) = o;
}

// ---------------- RoPE in-place on q and k, one launch ----------------------
__global__ __launch_bounds__(256) void rope2_k(bf16* __restrict__ qb,
                                               bf16* __restrict__ kb,
                                               const int* __restrict__ pos) {
  const int bid = blockIdx.x;
  bf16* x = (bid < 4096) ? qb : kb;
  int i = (bid & 4095) * 256 + threadIdx.x;   // 1,048,576 per tensor
  int g = i & 7;
  int row = i >> 3;                            // (b*16+h)*2048 + s
  int s = row & 2047;
  int b = row >> 15;
  float p = (float)pos[b * 2048 + s];
  bf16x8 v = *((bf16x8*)x + i);
  bf16x8 o;
#pragma unroll
  for (int j = 0; j < 4; j++) {
    int pp = g * 4 + j;
    float ang = p * exp2f((float)pp * -0.4152410118609203f);
    float sn, cs;
    sincosf(ang, &sn, &cs);
    float e = (float)v[2 * j], od = (float)v[2 * j + 1];
    o[2 * j]     = (bf16)(e * cs - od * sn);
    o[2 * j + 1] = (bf16)(e * sn + od * cs);
  }
  *((bf16x8*)x + i) = o;
}

// ---------------- NT GEMM, double-buffered LDS, counted vmcnt ---------------
// MODE 3: W = [3072][1024] fused wqkv; bn<8 -> q [b,h,s,dd], bn<16 -> k,
//         bn>=16 -> v transposed [b,h,dd,s]  (all bf16)
// MODE 2: W = [1024][1024]; f32 out [m][n]
template <int MODE>
__global__ __launch_bounds__(256) void gemm_nt(const bf16* __restrict__ A,
                                               const bf16* __restrict__ W,
                                               bf16* __restrict__ oq,
                                               bf16* __restrict__ ok,
                                               bf16* __restrict__ ov,
                                               float* __restrict__ outf) {
  constexpr int K = 1024;
  __shared__ bf16 As[2][4096];
  __shared__ bf16 Bs[2][4096];
  const int t = threadIdx.x;
  const int l = t & 63, wid = t >> 6;
  const int bm = blockIdx.x, bn = blockIdx.y;
  const int wm = wid >> 1, wn = wid & 1;

  f32x4 acc[4][4] = {};

  const bf16* aS = A + (size_t)(bm * 128 + (t >> 2)) * K + (t & 3) * 8;
  const bf16* bS = W + (size_t)(bn * 128 + (t >> 2)) * K + (t & 3) * 8;
  const int kc = (l >> 4) * 8;
  const int ar = wm * 64 + (l & 15);
  const int br = wn * 64 + (l & 15);

  auto stage = [&](int kt, int buf) {
    GLDS16(aS + kt, &As[buf][wid * 512]);
    GLDS16(aS + (size_t)64 * K + kt, &As[buf][2048 + wid * 512]);
    GLDS16(bS + kt, &Bs[buf][wid * 512]);
    GLDS16(bS + (size_t)64 * K + kt, &Bs[buf][2048 + wid * 512]);
  };

  auto gbody = [&](int step, int cur) {
    if (step < 31) {
      stage((step + 1) * 32, cur ^ 1);
      asm volatile("s_waitcnt vmcnt(4)" ::: "memory");
    } else {
      asm volatile("s_waitcnt vmcnt(0)" ::: "memory");
    }
    __builtin_amdgcn_s_barrier();
    __builtin_amdgcn_sched_barrier(0);
    bf16x8 af[4], bfr[4];
#pragma unroll
    for (int mi = 0; mi < 4; mi++)
      af[mi] = *(const bf16x8*)&As[cur][(ar + mi * 16) * 32 + kc];
#pragma unroll
    for (int ni = 0; ni < 4; ni++)
      bfr[ni] = *(const bf16x8*)&Bs[cur][(br + ni * 16) * 32 + kc];
#pragma unroll
    for (int mi = 0; mi < 4; mi++)
#pragma unroll
      for (int ni = 0; ni < 4; ni++)
        acc[mi][ni] = __builtin_amdgcn_mfma_f32_16x16x32_bf16(
            af[mi], bfr[ni], acc[mi][ni], 0, 0, 0);
    asm volatile("s_waitcnt lgkmcnt(0)" ::: "memory");
    __builtin_amdgcn_sched_barrier(0);
    __builtin_amdgcn_s_barrier();
  };

  stage(0, 0);
#pragma unroll 1
  for (int s2 = 0; s2 < 16; ++s2) {
    gbody(2 * s2, 0);
    gbody(2 * s2 + 1, 1);
  }

  const int rbase = bm * 128 + wm * 64 + (l >> 4) * 4;
  const int cbase = bn * 128 + wn * 64 + (l & 15);

  if (MODE == 3) {
    const int tsel = bn >> 3;   // uniform per block
    bf16* dst = (tsel == 0) ? oq : (tsel == 1) ? ok : ov;
#pragma unroll
    for (int mi = 0; mi < 4; mi++) {
#pragma unroll
      for (int ni = 0; ni < 4; ni++) {
#pragma unroll
        for (int r = 0; r < 4; r++) {
          int gm = rbase + mi * 16 + r;
          int col = (cbase + ni * 16) & 1023;
          size_t base = ((size_t)((gm >> 11) * 16 + (col >> 6)) << 17);
          size_t idx = (tsel < 2)
                           ? base + ((size_t)(gm & 2047) << 6) + (col & 63)
                           : base + ((size_t)(col & 63) << 11) + (gm & 2047);
          dst[idx] = (bf16)acc[mi][ni][r];
        }
      }
    }
  } else {
#pragma unroll
    for (int mi = 0; mi < 4; mi++)
#pragma unroll
      for (int ni = 0; ni < 4; ni++)
#pragma unroll
        for (int r = 0; r < 4; r++)
          outf[(size_t)(rbase + mi * 16 + r) * 1024 + cbase + ni * 16] =
              acc[mi][ni][r];
  }
}

// ---------------- causal flash attention, 32x32x16, 2-wave blocks -----------
// grid (16, B*H), 128 thr = 2 waves, each wave owns 32 q rows (QBLK=64).
// Block j does q-tiles {31-j, j} -> uniform 33 kv-tiles.
// Swapped QK^T (S^T = K·Q^T): lane owns q-col q5=l&31, kv reg-mapped.
// PV uses global kv-permutation sigma = swap(bit2<->bit3): A-frag becomes the
// natural packing of sc registers (no cross-lane), B-frag = 2 ds_read_b64.
// No max subtraction: P' = exp2(sc), uniform scale cancels in acc/l.
__global__ __launch_bounds__(128) void attn_k(const bf16* __restrict__ q,
                                              const bf16* __restrict__ k,
                                              const bf16* __restrict__ vt,
                                              bf16* __restrict__ att) {
  __shared__ bf16 Ks[2][4096];   // [buf][kv 64][d 64], rows XOR-swizzled
  __shared__ bf16 Vs[2][4096];   // [buf][d 64][kv 64], rows XOR-swizzled

  const int t = threadIdx.x, l = t & 63, w = t >> 6;
  const int hi2 = l >> 5, q5 = l & 31;

  const int raw = blockIdx.y * 16 + blockIdx.x;     // XCD-bijective swizzle
  const int wg = (raw & 7) * 128 + (raw >> 3);
  const int jq = wg & 15;
  const int bh = wg >> 4;

  const bf16* qb = q + (size_t)bh * S * 64;
  const bf16* kb = k + (size_t)bh * S * 64;
  const bf16* vb = vt + (size_t)bh * 64 * S;

  // staging: lane covers 16B chunk; row&7 == (l>>3)&7 (all bases mult of 8)
  const int srow = w * 32 + (l >> 3);
  const int clog = ((l & 7) ^ ((l >> 3) & 7)) * 8;  // pre-swizzled src chunk

  auto stage = [&](int nt, int b) {
#pragma unroll
    for (int g = 0; g < 4; g++)
      GLDS16(kb + (size_t)(nt * 64 + srow + 8 * g) * 64 + clog,
             &Ks[b][(w * 32 + 8 * g) * 64]);
#pragma unroll
    for (int g = 0; g < 4; g++)
      GLDS16(vb + (size_t)(srow + 8 * g) * S + nt * 64 + clog,
             &Vs[b][(w * 32 + 8 * g) * 64]);
  };

  // precomputed LDS byte offsets (loop-invariant)
  const int swz = (q5 & 7) << 4;
  int kaddr[4], vaddr[8];
#pragma unroll
  for (int c = 0; c < 4; c++)
    kaddr[c] = q5 * 128 + ((32 * c + 16 * hi2) ^ swz);
#pragma unroll
  for (int m = 0; m < 8; m++)
    vaddr[m] = q5 * 128 + ((16 * m) ^ swz) + 8 * hi2;

  const int b_ = bh >> 4, h_ = bh & 15;
  const char* KsB = (const char*)&Ks[0][0];
  const char* VsB = (const char*)&Vs[0][0];

  for (int pass = 0; pass < 2; ++pass) {
    const int qt = pass ? jq : 31 - jq;
    const int qrow = qt * 64 + w * 32 + q5;
    bf16x8 qf[4];   // Q^T B-operand, chunk c: d = 16c+8*hi2+(0..7); scaled
#pragma unroll
    for (int c = 0; c < 4; c++) {
      bf16x8 rq = *(const bf16x8*)&qb[(size_t)qrow * 64 + 16 * c + 8 * hi2];
      bf16x8 s_;
#pragma unroll
      for (int j2 = 0; j2 < 8; j2++)
        s_[j2] = (bf16)((float)rq[j2] * 0.18033688011112042f);
      qf[c] = s_;
    }

    f32x16 acc[2] = {};
    float l_r = 0.f;
    const int nkv = qt + 1;

    auto body = [&](int nt, int cur) {
      if (nt + 1 < nkv) {
        stage(nt + 1, cur ^ 1);
        asm volatile("s_waitcnt vmcnt(8)" ::: "memory");
      } else {
        asm volatile("s_waitcnt vmcnt(0)" ::: "memory");
      }
      __builtin_amdgcn_s_barrier();
      __builtin_amdgcn_sched_barrier(0);
      const int bo = cur * 8192;

      // S^T = K Q^T: tile T (kv 32T..32T+31), chain over c (d = 16c..)
      f32x16 sc[2] = {};
      __builtin_amdgcn_s_setprio(1);
#pragma unroll
      for (int c = 0; c < 4; c++) {
#pragma unroll
        for (int T = 0; T < 2; T++) {
          bf16x8 kf = *(const bf16x8*)(KsB + bo + T * 4096 + kaddr[c]);
          sc[T] = __builtin_amdgcn_mfma_f32_32x32x16_bf16(kf, qf[c], sc[T], 0, 0, 0);
        }
      }
      __builtin_amdgcn_s_setprio(0);

      if (nt == qt) {   // causal mask: kv_loc = 32T + (r&3)+8*(r>>2)+4*hi2
#pragma unroll
        for (int T = 0; T < 2; T++)
#pragma unroll
          for (int r = 0; r < 16; r++) {
            int kvloc = 32 * T + (r & 3) + 8 * (r >> 2) + 4 * hi2;
            if (kvloc > w * 32 + q5) sc[T][r] = -1e30f;
          }
      }

      // softmax (no max-subtract): P' = exp2(sc); row-sum in-lane + xor32
      float rs = 0.f;
#pragma unroll
      for (int T = 0; T < 2; T++)
#pragma unroll
        for (int r = 0; r < 16; r++) {
          float pv = __builtin_amdgcn_exp2f(sc[T][r]);
          sc[T][r] = pv;
          rs += pv;
        }
      rs += __shfl_xor(rs, 32);
      l_r += rs;

      // pack P: A-frag(c) = sc[c>>1] regs 8*(c&1)..+7 in natural order (sigma)
      bf16x8 pa[4];
#pragma unroll
      for (int c = 0; c < 4; c++)
#pragma unroll
        for (int j2 = 0; j2 < 8; j2++)
          pa[c][j2] = (bf16)sc[c >> 1][8 * (c & 1) + j2];

      // O += P'V: B-frag(c,dt) = V[sigma(16c+8hi2+j)][32dt+q5], 2x b64
      __builtin_amdgcn_s_setprio(1);
#pragma unroll
      for (int c = 0; c < 4; c++) {
#pragma unroll
        for (int dt = 0; dt < 2; dt++) {
          bf16x4 v0 = *(const bf16x4*)(VsB + bo + dt * 4096 + vaddr[2 * c]);
          bf16x4 v1 = *(const bf16x4*)(VsB + bo + dt * 4096 + vaddr[2 * c + 1]);
          bf16x8 bv;
#pragma unroll
          for (int j2 = 0; j2 < 4; j2++) { bv[j2] = v0[j2]; bv[4 + j2] = v1[j2]; }
          acc[dt] = __builtin_amdgcn_mfma_f32_32x32x16_bf16(pa[c], bv, acc[dt], 0, 0, 0);
        }
      }
      __builtin_amdgcn_s_setprio(0);

      asm volatile("s_waitcnt lgkmcnt(0)" ::: "memory");
      __builtin_amdgcn_sched_barrier(0);
      __builtin_amdgcn_s_barrier();
    };

    stage(0, 0);
    int nt = 0;
    for (; nt + 1 < nkv; nt += 2) {
      body(nt, 0);
      body(nt + 1, 1);
    }
    if (nt < nkv) body(nt, 0);

    // epilogue: O row = qt*64 + w*32 + rmap(r,hi2), col d = 32dt + q5
    float linv = 1.f / l_r;
#pragma unroll
    for (int r = 0; r < 16; r++) {
      int rmap = (r & 3) + 8 * (r >> 2) + 4 * hi2;
      float li = __shfl(linv, rmap);
      int rowq = qt * 64 + w * 32 + rmap;
      size_t rb = ((size_t)(b_ * S + rowq) << 10) + h_ * 64 + q5;
#pragma unroll
      for (int dt = 0; dt < 2; dt++)
        att[rb + 32 * dt] = (bf16)(acc[dt][r] * li);
    }
  }
}

extern "C" void kernel_launch(void* const* d_in, const int* in_sizes, int n_in,
                              void* d_out, int out_size, void* d_ws, size_t ws_size,
                              hipStream_t stream) {
  const float* x  = (const float*)d_in[0];
  const int* tp   = (const int*)d_in[1];
  const float* wq = (const float*)d_in[2];
  const float* wk = (const float*)d_in[3];
  const float* wv = (const float*)d_in[4];
  const float* wo = (const float*)d_in[5];
  float* out = (float*)d_out;

  char* ws = (char*)d_ws;
  const size_t TEN = 16777216;  // 8192*1024*2 bytes
  bf16* x_bf    = (bf16*)(ws);
  bf16* q_bf    = (bf16*)(ws + TEN);
  bf16* k_bf    = (bf16*)(ws + 2 * TEN);
  bf16* v_bf    = (bf16*)(ws + 3 * TEN);
  bf16* wqkv_bf = (bf16*)(ws + 4 * TEN);          // 3072x1024 = 6MB
  bf16* wo_bf   = wqkv_bf + 3 * 1048576;          // 2MB
  bf16* att_bf  = x_bf;   // alias: x_bf dead after QKV projection

  cvt_all<<<6144, 256, 0, stream>>>(x, wq, wk, wv, wo, x_bf, wqkv_bf, wo_bf);

  dim3 gq(64, 24);
  gemm_nt<3><<<gq, 256, 0, stream>>>(x_bf, wqkv_bf, q_bf, k_bf, v_bf, nullptr);

  rope2_k<<<8192, 256, 0, stream>>>(q_bf, k_bf, tp);

  dim3 ga(16, 64);
  attn_k<<<ga, 128, 0, stream>>>(q_bf, k_bf, v_bf, att_bf);

  dim3 go(64, 8);
  gemm_nt<2><<<go, 256, 0, stream>>>(att_bf, wo_bf, nullptr, nullptr, nullptr, out);
}

// Round 5
// 190.412 us; speedup vs baseline: 1.1558x; 1.1558x over previous
//
#include <hip/hip_runtime.h>
#include <hip/hip_bf16.h>
#include <stdint.h>

typedef __bf16 bf16;
typedef __bf16 bf16x4 __attribute__((ext_vector_type(4)));
typedef __bf16 bf16x8 __attribute__((ext_vector_type(8)));
typedef float f32x4 __attribute__((ext_vector_type(4)));
typedef float f32x16 __attribute__((ext_vector_type(16)));

#define GLDS16(g, l) __builtin_amdgcn_global_load_lds( \
    (const __attribute__((address_space(1))) void*)(g), \
    (__attribute__((address_space(3))) void*)(l), 16, 0, 0)

static constexpr int S = 2048;

// ---------------- fused f32 -> bf16 convert: x + 4 weights, 1 launch --------
__global__ __launch_bounds__(256) void cvt_all(const float* __restrict__ x,
                                               const float* __restrict__ wq,
                                               const float* __restrict__ wk,
                                               const float* __restrict__ wv,
                                               const float* __restrict__ wo,
                                               bf16* __restrict__ xb,
                                               bf16* __restrict__ wqkvb,
                                               bf16* __restrict__ wob) {
  const int bid = blockIdx.x;
  const float* src;
  bf16* dst;
  int i;
  if (bid < 4096) {            // x: 1,048,576 groups of 8
    src = x; dst = xb; i = bid * 256 + threadIdx.x;
  } else {                     // weights: 131,072 groups each
    int w = (bid - 4096) >> 9;
    i = ((bid - 4096) & 511) * 256 + threadIdx.x;
    src = (w == 0) ? wq : (w == 1) ? wk : (w == 2) ? wv : wo;
    dst = (w == 3) ? wob : wqkvb + (size_t)w * 1048576;
  }
  const float4* p = (const float4*)src + (size_t)i * 2;
  float4 a = p[0], b = p[1];
  bf16x8 o;
  o[0] = (bf16)a.x; o[1] = (bf16)a.y; o[2] = (bf16)a.z; o[3] = (bf16)a.w;
  o[4] = (bf16)b.x; o[5] = (bf16)b.y; o[6] = (bf16)b.z; o[7] = (bf16)b.w;
  *((bf16x8*)dst + i) = o;
}

// ---------------- RoPE in-place on q and k, one launch ----------------------
__global__ __launch_bounds__(256) void rope2_k(bf16* __restrict__ qb,
                                               bf16* __restrict__ kb,
                                               const int* __restrict__ pos) {
  const int bid = blockIdx.x;
  bf16* x = (bid < 4096) ? qb : kb;
  int i = (bid & 4095) * 256 + threadIdx.x;   // 1,048,576 per tensor
  int g = i & 7;
  int row = i >> 3;                            // (b*16+h)*2048 + s
  int s = row & 2047;
  int b = row >> 15;
  float p = (float)pos[b * 2048 + s];
  bf16x8 v = *((bf16x8*)x + i);
  bf16x8 o;
#pragma unroll
  for (int j = 0; j < 4; j++) {
    int pp = g * 4 + j;
    float ang = p * exp2f((float)pp * -0.4152410118609203f);
    float sn, cs;
    sincosf(ang, &sn, &cs);
    float e = (float)v[2 * j], od = (float)v[2 * j + 1];
    o[2 * j]     = (bf16)(e * cs - od * sn);
    o[2 * j + 1] = (bf16)(e * sn + od * cs);
  }
  *((bf16x8*)x + i) = o;
}

// ---------------- NT GEMM, double-buffered LDS, counted vmcnt ---------------
// MODE 3: W = [3072][1024] fused wqkv; bn<8 -> q [b,h,s,dd], bn<16 -> k,
//         bn>=16 -> v transposed [b,h,dd,s]  (all bf16)
// MODE 2: W = [1024][1024]; f32 out [m][n]
template <int MODE>
__global__ __launch_bounds__(256) void gemm_nt(const bf16* __restrict__ A,
                                               const bf16* __restrict__ W,
                                               bf16* __restrict__ oq,
                                               bf16* __restrict__ ok,
                                               bf16* __restrict__ ov,
                                               float* __restrict__ outf) {
  constexpr int K = 1024;
  __shared__ bf16 As[2][4096];
  __shared__ bf16 Bs[2][4096];
  const int t = threadIdx.x;
  const int l = t & 63, wid = t >> 6;
  const int bm = blockIdx.x, bn = blockIdx.y;
  const int wm = wid >> 1, wn = wid & 1;

  f32x4 acc[4][4] = {};

  const bf16* aS = A + (size_t)(bm * 128 + (t >> 2)) * K + (t & 3) * 8;
  const bf16* bS = W + (size_t)(bn * 128 + (t >> 2)) * K + (t & 3) * 8;
  const int kc = (l >> 4) * 8;
  const int ar = wm * 64 + (l & 15);
  const int br = wn * 64 + (l & 15);

  auto stage = [&](int kt, int buf) {
    GLDS16(aS + kt, &As[buf][wid * 512]);
    GLDS16(aS + (size_t)64 * K + kt, &As[buf][2048 + wid * 512]);
    GLDS16(bS + kt, &Bs[buf][wid * 512]);
    GLDS16(bS + (size_t)64 * K + kt, &Bs[buf][2048 + wid * 512]);
  };

  auto gbody = [&](int step, int cur) {
    if (step < 31) {
      stage((step + 1) * 32, cur ^ 1);
      asm volatile("s_waitcnt vmcnt(4)" ::: "memory");
    } else {
      asm volatile("s_waitcnt vmcnt(0)" ::: "memory");
    }
    __builtin_amdgcn_s_barrier();
    __builtin_amdgcn_sched_barrier(0);
    bf16x8 af[4], bfr[4];
#pragma unroll
    for (int mi = 0; mi < 4; mi++)
      af[mi] = *(const bf16x8*)&As[cur][(ar + mi * 16) * 32 + kc];
#pragma unroll
    for (int ni = 0; ni < 4; ni++)
      bfr[ni] = *(const bf16x8*)&Bs[cur][(br + ni * 16) * 32 + kc];
#pragma unroll
    for (int mi = 0; mi < 4; mi++)
#pragma unroll
      for (int ni = 0; ni < 4; ni++)
        acc[mi][ni] = __builtin_amdgcn_mfma_f32_16x16x32_bf16(
            af[mi], bfr[ni], acc[mi][ni], 0, 0, 0);
    asm volatile("s_waitcnt lgkmcnt(0)" ::: "memory");
    __builtin_amdgcn_sched_barrier(0);
    __builtin_amdgcn_s_barrier();
  };

  stage(0, 0);
#pragma unroll 1
  for (int s2 = 0; s2 < 16; ++s2) {
    gbody(2 * s2, 0);
    gbody(2 * s2 + 1, 1);
  }

  const int rbase = bm * 128 + wm * 64 + (l >> 4) * 4;
  const int cbase = bn * 128 + wn * 64 + (l & 15);

  if (MODE == 3) {
    const int tsel = bn >> 3;   // uniform per block
    bf16* dst = (tsel == 0) ? oq : (tsel == 1) ? ok : ov;
#pragma unroll
    for (int mi = 0; mi < 4; mi++) {
#pragma unroll
      for (int ni = 0; ni < 4; ni++) {
#pragma unroll
        for (int r = 0; r < 4; r++) {
          int gm = rbase + mi * 16 + r;
          int col = (cbase + ni * 16) & 1023;
          size_t base = ((size_t)((gm >> 11) * 16 + (col >> 6)) << 17);
          size_t idx = (tsel < 2)
                           ? base + ((size_t)(gm & 2047) << 6) + (col & 63)
                           : base + ((size_t)(col & 63) << 11) + (gm & 2047);
          dst[idx] = (bf16)acc[mi][ni][r];
        }
      }
    }
  } else {
#pragma unroll
    for (int mi = 0; mi < 4; mi++)
#pragma unroll
      for (int ni = 0; ni < 4; ni++)
#pragma unroll
        for (int r = 0; r < 4; r++)
          outf[(size_t)(rbase + mi * 16 + r) * 1024 + cbase + ni * 16] =
              acc[mi][ni][r];
  }
}

// ---------------- causal flash attention, 32x32x16, 8-wave QBLK=256 ---------
// grid (4, B*H), 512 thr = 8 waves, each wave owns 32 q rows (QBLK=256).
// Block j does q-tiles {7-j, j} -> uniform 36 kv-tiles. KVBLK=64.
// 3-deep circular K/V prefetch (vmcnt(4)): tile data issued 2 bodies ahead.
// Swapped QK^T: lane owns q-col q5; PV uses sigma=swap(bit2<->bit3) on kv so
// P-A-frag is the natural sc register packing (no cross-lane, no LDS for P).
// No max-subtract: P' = exp2(sc) (scores bounded ~13), scale cancels in O/l.
__global__ __launch_bounds__(512) void attn_k(const bf16* __restrict__ q,
                                              const bf16* __restrict__ k,
                                              const bf16* __restrict__ vt,
                                              bf16* __restrict__ att) {
  __shared__ bf16 Ks[3][4096];   // [buf][kv 64][d 64], rows XOR-swizzled
  __shared__ bf16 Vs[3][4096];   // [buf][d 64][kv 64], rows XOR-swizzled

  const int t = threadIdx.x, l = t & 63, w = t >> 6;   // w = 0..7
  const int hi2 = l >> 5, q5 = l & 31;

  const int raw = blockIdx.y * 4 + blockIdx.x;   // 0..255
  const int wg = (raw & 7) * 32 + (raw >> 3);    // XCD-bijective: 8 bh per XCD
  const int j_ = wg & 3;
  const int bh = wg >> 2;

  const bf16* qb = q + (size_t)bh * S * 64;
  const bf16* kb = k + (size_t)bh * S * 64;
  const bf16* vb = vt + (size_t)bh * 64 * S;

  // staging: wave w covers rows 8w..8w+7; lane l -> row 8w+(l>>3), chunk l&7
  const int lrow = l >> 3;
  const int clog = ((l & 7) ^ (lrow & 7)) * 8;   // pre-swizzled source chunk

  auto stage = [&](int nt, int b) {
    GLDS16(kb + (size_t)(nt * 64 + w * 8 + lrow) * 64 + clog, &Ks[b][w * 512]);
    GLDS16(vb + (size_t)(w * 8 + lrow) * S + nt * 64 + clog, &Vs[b][w * 512]);
  };

  // precomputed LDS byte offsets (loop-invariant, within one 8192B buffer)
  const int swz = (q5 & 7) << 4;
  int kaddr[4], vaddr[8];
#pragma unroll
  for (int c = 0; c < 4; c++)
    kaddr[c] = q5 * 128 + ((32 * c + 16 * hi2) ^ swz);
#pragma unroll
  for (int m = 0; m < 8; m++)
    vaddr[m] = q5 * 128 + ((16 * m) ^ swz) + 8 * hi2;

  const int b_ = bh >> 4, h_ = bh & 15;
  const char* KsB = (const char*)&Ks[0][0];
  const char* VsB = (const char*)&Vs[0][0];

  for (int pass = 0; pass < 2; ++pass) {
    const int qt = pass ? j_ : 7 - j_;
    const int qrow = qt * 256 + w * 32 + q5;
    bf16x8 qf[4];   // Q^T B-operand, chunk c: d = 16c+8*hi2+(0..7); scaled
#pragma unroll
    for (int c = 0; c < 4; c++) {
      bf16x8 rq = *(const bf16x8*)&qb[(size_t)qrow * 64 + 16 * c + 8 * hi2];
      bf16x8 s_;
#pragma unroll
      for (int j2 = 0; j2 < 8; j2++)
        s_[j2] = (bf16)((float)rq[j2] * 0.18033688011112042f);
      qf[c] = s_;
    }

    f32x16 acc[2] = {};
    float l_r = 0.f;
    const int nkv = 4 * qt + 4;
    const int qmaxw = qt * 256 + w * 32 + 31;   // max q row of this wave

    int cur = 0, nxt = 1, ovr = 2;
    stage(0, 0);
    stage(1, 1);
#pragma unroll 1
    for (int nt = 0; nt < nkv; ++nt) {
      if (nt + 2 < nkv) {
        stage(nt + 2, ovr);
        asm volatile("s_waitcnt vmcnt(4)" ::: "memory");
      } else if (nt + 1 < nkv) {
        asm volatile("s_waitcnt vmcnt(2)" ::: "memory");
      } else {
        asm volatile("s_waitcnt vmcnt(0)" ::: "memory");
      }
      __builtin_amdgcn_s_barrier();
      __builtin_amdgcn_sched_barrier(0);

      const bool live = (64 * nt) <= qmaxw;
      if (live) {
        const int bo = cur * 8192;

        // S^T = K Q^T: half-tile T (kv 32T..+31), chain over c (d = 16c..)
        f32x16 sc[2] = {};
        __builtin_amdgcn_s_setprio(1);
#pragma unroll
        for (int c = 0; c < 4; c++) {
#pragma unroll
          for (int T = 0; T < 2; T++) {
            bf16x8 kf = *(const bf16x8*)(KsB + bo + T * 4096 + kaddr[c]);
            sc[T] = __builtin_amdgcn_mfma_f32_32x32x16_bf16(kf, qf[c], sc[T], 0, 0, 0);
          }
        }
        __builtin_amdgcn_s_setprio(0);

        if (64 * nt + 63 > qt * 256 + w * 32) {   // diagonal: causal mask
#pragma unroll
          for (int T = 0; T < 2; T++)
#pragma unroll
            for (int r = 0; r < 16; r++) {
              int kvg = 64 * nt + 32 * T + (r & 3) + 8 * (r >> 2) + 4 * hi2;
              if (kvg > qrow) sc[T][r] = -1e30f;
            }
        }

        // softmax (no max-subtract): P' = exp2(sc); row-sum in-lane + xor32
        float rs = 0.f;
#pragma unroll
        for (int T = 0; T < 2; T++)
#pragma unroll
          for (int r = 0; r < 16; r++) {
            float pv = __builtin_amdgcn_exp2f(sc[T][r]);
            sc[T][r] = pv;
            rs += pv;
          }
        rs += __shfl_xor(rs, 32);
        l_r += rs;

        // pack P: A-frag(c) = sc[c>>1] regs 8*(c&1)..+7 natural order (sigma)
        bf16x8 pa[4];
#pragma unroll
        for (int c = 0; c < 4; c++)
#pragma unroll
          for (int j2 = 0; j2 < 8; j2++)
            pa[c][j2] = (bf16)sc[c >> 1][8 * (c & 1) + j2];

        // O += P'V: B-frag(c,dt) = V[sigma(16c+8hi2+j)][32dt+q5], 2x b64
        __builtin_amdgcn_s_setprio(1);
#pragma unroll
        for (int c = 0; c < 4; c++) {
#pragma unroll
          for (int dt = 0; dt < 2; dt++) {
            bf16x4 v0 = *(const bf16x4*)(VsB + bo + dt * 4096 + vaddr[2 * c]);
            bf16x4 v1 = *(const bf16x4*)(VsB + bo + dt * 4096 + vaddr[2 * c + 1]);
            bf16x8 bv;
#pragma unroll
            for (int j2 = 0; j2 < 4; j2++) { bv[j2] = v0[j2]; bv[4 + j2] = v1[j2]; }
            acc[dt] = __builtin_amdgcn_mfma_f32_32x32x16_bf16(pa[c], bv, acc[dt], 0, 0, 0);
          }
        }
        __builtin_amdgcn_s_setprio(0);
      }

      asm volatile("s_waitcnt lgkmcnt(0)" ::: "memory");
      __builtin_amdgcn_sched_barrier(0);
      __builtin_amdgcn_s_barrier();
      int t3 = cur; cur = nxt; nxt = ovr; ovr = t3;
    }

    // epilogue: O row = qt*256 + w*32 + rmap(r,hi2), col d = 32dt + q5
    float linv = 1.f / l_r;
#pragma unroll
    for (int r = 0; r < 16; r++) {
      int rmap = (r & 3) + 8 * (r >> 2) + 4 * hi2;
      float li = __shfl(linv, rmap);
      int rowq = qt * 256 + w * 32 + rmap;
      size_t rb = ((size_t)(b_ * S + rowq) << 10) + h_ * 64 + q5;
#pragma unroll
      for (int dt = 0; dt < 2; dt++)
        att[rb + 32 * dt] = (bf16)(acc[dt][r] * li);
    }
  }
}

extern "C" void kernel_launch(void* const* d_in, const int* in_sizes, int n_in,
                              void* d_out, int out_size, void* d_ws, size_t ws_size,
                              hipStream_t stream) {
  const float* x  = (const float*)d_in[0];
  const int* tp   = (const int*)d_in[1];
  const float* wq = (const float*)d_in[2];
  const float* wk = (const float*)d_in[3];
  const float* wv = (const float*)d_in[4];
  const float* wo = (const float*)d_in[5];
  float* out = (float*)d_out;

  char* ws = (char*)d_ws;
  const size_t TEN = 16777216;  // 8192*1024*2 bytes
  bf16* x_bf    = (bf16*)(ws);
  bf16* q_bf    = (bf16*)(ws + TEN);
  bf16* k_bf    = (bf16*)(ws + 2 * TEN);
  bf16* v_bf    = (bf16*)(ws + 3 * TEN);
  bf16* wqkv_bf = (bf16*)(ws + 4 * TEN);          // 3072x1024 = 6MB
  bf16* wo_bf   = wqkv_bf + 3 * 1048576;          // 2MB
  bf16* att_bf  = x_bf;   // alias: x_bf dead after QKV projection

  cvt_all<<<6144, 256, 0, stream>>>(x, wq, wk, wv, wo, x_bf, wqkv_bf, wo_bf);

  dim3 gq(64, 24);
  gemm_nt<3><<<gq, 256, 0, stream>>>(x_bf, wqkv_bf, q_bf, k_bf, v_bf, nullptr);

  rope2_k<<<8192, 256, 0, stream>>>(q_bf, k_bf, tp);

  dim3 ga(4, 64);
  attn_k<<<ga, 512, 0, stream>>>(q_bf, k_bf, v_bf, att_bf);

  dim3 go(64, 8);
  gemm_nt<2><<<go, 256, 0, stream>>>(att_bf, wo_bf, nullptr, nullptr, nullptr, out);
}

// Round 6
// 190.102 us; speedup vs baseline: 1.1577x; 1.0016x over previous
//
#include <hip/hip_runtime.h>
#include <hip/hip_bf16.h>
#include <stdint.h>

typedef __bf16 bf16;
typedef __bf16 bf16x4 __attribute__((ext_vector_type(4)));
typedef __bf16 bf16x8 __attribute__((ext_vector_type(8)));
typedef float f32x4 __attribute__((ext_vector_type(4)));
typedef float f32x16 __attribute__((ext_vector_type(16)));

#define GLDS16(g, l) __builtin_amdgcn_global_load_lds( \
    (const __attribute__((address_space(1))) void*)(g), \
    (__attribute__((address_space(3))) void*)(l), 16, 0, 0)

static constexpr int S = 2048;

// ---------------- fused f32 -> bf16 convert: x + 4 weights, 1 launch --------
__global__ __launch_bounds__(256) void cvt_all(const float* __restrict__ x,
                                               const float* __restrict__ wq,
                                               const float* __restrict__ wk,
                                               const float* __restrict__ wv,
                                               const float* __restrict__ wo,
                                               bf16* __restrict__ xb,
                                               bf16* __restrict__ wqkvb,
                                               bf16* __restrict__ wob) {
  const int bid = blockIdx.x;
  const float* src;
  bf16* dst;
  int i;
  if (bid < 4096) {            // x: 1,048,576 groups of 8
    src = x; dst = xb; i = bid * 256 + threadIdx.x;
  } else {                     // weights: 131,072 groups each
    int w = (bid - 4096) >> 9;
    i = ((bid - 4096) & 511) * 256 + threadIdx.x;
    src = (w == 0) ? wq : (w == 1) ? wk : (w == 2) ? wv : wo;
    dst = (w == 3) ? wob : wqkvb + (size_t)w * 1048576;
  }
  const float4* p = (const float4*)src + (size_t)i * 2;
  float4 a = p[0], b = p[1];
  bf16x8 o;
  o[0] = (bf16)a.x; o[1] = (bf16)a.y; o[2] = (bf16)a.z; o[3] = (bf16)a.w;
  o[4] = (bf16)b.x; o[5] = (bf16)b.y; o[6] = (bf16)b.z; o[7] = (bf16)b.w;
  *((bf16x8*)dst + i) = o;
}

// ---------------- RoPE in-place on q and k, one launch ----------------------
__global__ __launch_bounds__(256) void rope2_k(bf16* __restrict__ qb,
                                               bf16* __restrict__ kb,
                                               const int* __restrict__ pos) {
  const int bid = blockIdx.x;
  bf16* x = (bid < 4096) ? qb : kb;
  int i = (bid & 4095) * 256 + threadIdx.x;   // 1,048,576 per tensor
  int g = i & 7;
  int row = i >> 3;                            // (b*16+h)*2048 + s
  int s = row & 2047;
  int b = row >> 15;
  float p = (float)pos[b * 2048 + s];
  bf16x8 v = *((bf16x8*)x + i);
  bf16x8 o;
#pragma unroll
  for (int j = 0; j < 4; j++) {
    int pp = g * 4 + j;
    float ang = p * exp2f((float)pp * -0.4152410118609203f);
    float sn, cs;
    sincosf(ang, &sn, &cs);
    float e = (float)v[2 * j], od = (float)v[2 * j + 1];
    o[2 * j]     = (bf16)(e * cs - od * sn);
    o[2 * j + 1] = (bf16)(e * sn + od * cs);
  }
  *((bf16x8*)x + i) = o;
}

// ---------------- NT GEMM: 256x128 tile, BK=64, 8 waves, 4-phase ------------
// 3-buffer LDS ring (144 KB), XOR-swizzled rows (conflict-free ds_read_b128),
// counted vmcnt(6) boundary (whole next tile landed), per-phase
// {ds_read || global_load_lds -> barrier -> lgkm(0) -> setprio MFMA} schedule.
// MODE 3: W = [3072][1024] fused wqkv; bn<8 -> q [b,h,s,dd], bn<16 -> k,
//         bn>=16 -> v transposed [b,h,dd,s]  (all bf16)
// MODE 2: W = [1024][1024]; f32 out [m][n]
template <int MODE>
__global__ __launch_bounds__(512) void gemm_nt(const bf16* __restrict__ A,
                                               const bf16* __restrict__ W,
                                               bf16* __restrict__ oq,
                                               bf16* __restrict__ ok,
                                               bf16* __restrict__ ov,
                                               float* __restrict__ outf) {
  constexpr int K = 1024, NK = 16;
  __shared__ bf16 As[3][16384];   // [buf][256 rows][64 cols] swizzled (32 KB)
  __shared__ bf16 Bs[3][8192];    // [buf][128 rows][64 cols] swizzled (16 KB)
  const int t = threadIdx.x, l = t & 63, wid = t >> 6;
  const int wm = wid >> 1, wn = wid & 1;   // 4M x 2N waves, 64x64 per wave
  const int bm = blockIdx.x, bn = blockIdx.y;

  f32x4 acc[4][4] = {};

  // staging: wave stages A rows wid*32..+31 (4 groups of 8), B rows wid*16..+15
  const int lrow = l >> 3;
  const int cswz = ((l & 7) ^ (lrow & 7)) * 8;   // pre-swizzled source chunk
  const bf16* aS = A + (size_t)(bm * 256 + wid * 32 + lrow) * K + cswz;
  const bf16* bS = W + (size_t)(bn * 128 + wid * 16 + lrow) * K + cswz;

  auto sA = [&](int kt, int buf, int g) {
    GLDS16(aS + (size_t)(8 * g) * K + kt, &As[buf][(wid * 32 + 8 * g) * 64]);
  };
  auto sB = [&](int kt, int buf, int g) {
    GLDS16(bS + (size_t)(8 * g) * K + kt, &Bs[buf][(wid * 16 + 8 * g) * 64]);
  };

  // loop-invariant LDS byte offsets: frag f, kchunk kk
  int offA[4][2], offB[4][2];
#pragma unroll
  for (int f = 0; f < 4; f++)
#pragma unroll
    for (int kk = 0; kk < 2; kk++) {
      int ra = wm * 64 + f * 16 + (l & 15);
      offA[f][kk] = ra * 128 + 16 * ((kk * 4 + (l >> 4)) ^ (ra & 7));
      int rb = wn * 64 + f * 16 + (l & 15);
      offB[f][kk] = rb * 128 + 16 * ((kk * 4 + (l >> 4)) ^ (rb & 7));
    }

  // prologue: stage tiles 0 and 1; wait tile 0 landed (leave tile 1 in flight)
#pragma unroll
  for (int g = 0; g < 4; g++) sA(0, 0, g);
  sB(0, 0, 0); sB(0, 0, 1);
#pragma unroll
  for (int g = 0; g < 4; g++) sA(64, 1, g);
  sB(64, 1, 0); sB(64, 1, 1);
  asm volatile("s_waitcnt vmcnt(6)" ::: "memory");
  __builtin_amdgcn_s_barrier();

  int cur = 0, nxt = 1, ovr = 2;
#pragma unroll 1
  for (int t_ = 0; t_ < NK; ++t_) {
    const int kt2 = (t_ + 2) * 64;
    const bool st = (t_ + 2) < NK;
    const char* Ap = (const char*)&As[cur][0];
    const char* Bp = (const char*)&Bs[cur][0];
    bf16x8 a0[2][2], a1[2][2], b0[2][2], b1[2][2];

    // ---- P0: read A-half0 + B-half0; stage A g0,g1; MFMA M0 x N0
#pragma unroll
    for (int f = 0; f < 2; f++)
#pragma unroll
      for (int kk = 0; kk < 2; kk++) {
        a0[f][kk] = *(const bf16x8*)(Ap + offA[f][kk]);
        b0[f][kk] = *(const bf16x8*)(Bp + offB[f][kk]);
      }
    if (st) { sA(kt2, ovr, 0); sA(kt2, ovr, 1); }
    __builtin_amdgcn_s_barrier();
    asm volatile("s_waitcnt lgkmcnt(0)" ::: "memory");
    __builtin_amdgcn_sched_barrier(0);
    __builtin_amdgcn_s_setprio(1);
#pragma unroll
    for (int mi = 0; mi < 2; mi++)
#pragma unroll
      for (int ni = 0; ni < 2; ni++)
#pragma unroll
        for (int kk = 0; kk < 2; kk++)
          acc[mi][ni] = __builtin_amdgcn_mfma_f32_16x16x32_bf16(
              a0[mi][kk], b0[ni][kk], acc[mi][ni], 0, 0, 0);
    __builtin_amdgcn_s_setprio(0);
    __builtin_amdgcn_s_barrier();

    // ---- P1: read B-half1; stage A g2,g3; MFMA M0 x N1
#pragma unroll
    for (int f = 0; f < 2; f++)
#pragma unroll
      for (int kk = 0; kk < 2; kk++)
        b1[f][kk] = *(const bf16x8*)(Bp + offB[2 + f][kk]);
    if (st) { sA(kt2, ovr, 2); sA(kt2, ovr, 3); }
    __builtin_amdgcn_s_barrier();
    asm volatile("s_waitcnt lgkmcnt(0)" ::: "memory");
    __builtin_amdgcn_sched_barrier(0);
    __builtin_amdgcn_s_setprio(1);
#pragma unroll
    for (int mi = 0; mi < 2; mi++)
#pragma unroll
      for (int ni = 0; ni < 2; ni++)
#pragma unroll
        for (int kk = 0; kk < 2; kk++)
          acc[mi][2 + ni] = __builtin_amdgcn_mfma_f32_16x16x32_bf16(
              a0[mi][kk], b1[ni][kk], acc[mi][2 + ni], 0, 0, 0);
    __builtin_amdgcn_s_setprio(0);
    __builtin_amdgcn_s_barrier();

    // ---- P2: read A-half1; stage B g0,g1; MFMA M1 x N1
#pragma unroll
    for (int f = 0; f < 2; f++)
#pragma unroll
      for (int kk = 0; kk < 2; kk++)
        a1[f][kk] = *(const bf16x8*)(Ap + offA[2 + f][kk]);
    if (st) { sB(kt2, ovr, 0); sB(kt2, ovr, 1); }
    __builtin_amdgcn_s_barrier();
    asm volatile("s_waitcnt lgkmcnt(0)" ::: "memory");
    __builtin_amdgcn_sched_barrier(0);
    __builtin_amdgcn_s_setprio(1);
#pragma unroll
    for (int mi = 0; mi < 2; mi++)
#pragma unroll
      for (int ni = 0; ni < 2; ni++)
#pragma unroll
        for (int kk = 0; kk < 2; kk++)
          acc[2 + mi][2 + ni] = __builtin_amdgcn_mfma_f32_16x16x32_bf16(
              a1[mi][kk], b1[ni][kk], acc[2 + mi][2 + ni], 0, 0, 0);
    __builtin_amdgcn_s_setprio(0);
    __builtin_amdgcn_s_barrier();

    // ---- P3: MFMA M1 x N0 (regs only); counted boundary vmcnt; barrier
    __builtin_amdgcn_s_setprio(1);
#pragma unroll
    for (int mi = 0; mi < 2; mi++)
#pragma unroll
      for (int ni = 0; ni < 2; ni++)
#pragma unroll
        for (int kk = 0; kk < 2; kk++)
          acc[2 + mi][ni] = __builtin_amdgcn_mfma_f32_16x16x32_bf16(
              a1[mi][kk], b0[ni][kk], acc[2 + mi][ni], 0, 0, 0);
    __builtin_amdgcn_s_setprio(0);
    if (st) {
      asm volatile("s_waitcnt vmcnt(6)" ::: "memory");
    } else {
      asm volatile("s_waitcnt vmcnt(0)" ::: "memory");
    }
    __builtin_amdgcn_s_barrier();
    int tmp = cur; cur = nxt; nxt = ovr; ovr = tmp;
  }

  const int rbase = bm * 256 + wm * 64 + (l >> 4) * 4;
#pragma unroll
  for (int mi = 0; mi < 4; mi++) {
#pragma unroll
    for (int ni = 0; ni < 4; ni++) {
      const int cl = wn * 64 + ni * 16 + (l & 15);   // 0..127 within tile
#pragma unroll
      for (int r = 0; r < 4; r++) {
        int gm = rbase + mi * 16 + r;
        float v = acc[mi][ni][r];
        if (MODE == 3) {
          int tsel = bn >> 3;
          int ct = (bn & 7) * 128 + cl;              // 0..1023 within tensor
          bf16* dst = (tsel == 0) ? oq : (tsel == 1) ? ok : ov;
          size_t base = ((size_t)((gm >> 11) * 16 + (ct >> 6)) << 17);
          size_t idx = (tsel < 2)
                           ? base + ((size_t)(gm & 2047) << 6) + (ct & 63)
                           : base + ((size_t)(ct & 63) << 11) + (gm & 2047);
          dst[idx] = (bf16)v;
        } else {
          outf[(size_t)gm * 1024 + bn * 128 + cl] = v;
        }
      }
    }
  }
}

// ---------------- causal flash attention, 32x32x16, 8-wave QBLK=256 ---------
// grid (4, B*H), 512 thr = 8 waves, each wave owns 32 q rows (QBLK=256).
// Block j does q-tiles {7-j, j} -> uniform 36 kv-tiles. KVBLK=64.
// 3-deep circular K/V prefetch (vmcnt(4)): tile data issued 2 bodies ahead.
// Swapped QK^T: lane owns q-col q5; PV uses sigma=swap(bit2<->bit3) on kv so
// P-A-frag is the natural sc register packing (no cross-lane, no LDS for P).
// No max-subtract: P' = exp2(sc) (scores bounded ~13), scale cancels in O/l.
__global__ __launch_bounds__(512) void attn_k(const bf16* __restrict__ q,
                                              const bf16* __restrict__ k,
                                              const bf16* __restrict__ vt,
                                              bf16* __restrict__ att) {
  __shared__ bf16 Ks[3][4096];   // [buf][kv 64][d 64], rows XOR-swizzled
  __shared__ bf16 Vs[3][4096];   // [buf][d 64][kv 64], rows XOR-swizzled

  const int t = threadIdx.x, l = t & 63, w = t >> 6;   // w = 0..7
  const int hi2 = l >> 5, q5 = l & 31;

  const int raw = blockIdx.y * 4 + blockIdx.x;   // 0..255
  const int wg = (raw & 7) * 32 + (raw >> 3);    // XCD-bijective: 8 bh per XCD
  const int j_ = wg & 3;
  const int bh = wg >> 2;

  const bf16* qb = q + (size_t)bh * S * 64;
  const bf16* kb = k + (size_t)bh * S * 64;
  const bf16* vb = vt + (size_t)bh * 64 * S;

  // staging: wave w covers rows 8w..8w+7; lane l -> row 8w+(l>>3), chunk l&7
  const int lrow = l >> 3;
  const int clog = ((l & 7) ^ (lrow & 7)) * 8;   // pre-swizzled source chunk

  auto stage = [&](int nt, int b) {
    GLDS16(kb + (size_t)(nt * 64 + w * 8 + lrow) * 64 + clog, &Ks[b][w * 512]);
    GLDS16(vb + (size_t)(w * 8 + lrow) * S + nt * 64 + clog, &Vs[b][w * 512]);
  };

  // precomputed LDS byte offsets (loop-invariant, within one 8192B buffer)
  const int swz = (q5 & 7) << 4;
  int kaddr[4], vaddr[8];
#pragma unroll
  for (int c = 0; c < 4; c++)
    kaddr[c] = q5 * 128 + ((32 * c + 16 * hi2) ^ swz);
#pragma unroll
  for (int m = 0; m < 8; m++)
    vaddr[m] = q5 * 128 + ((16 * m) ^ swz) + 8 * hi2;

  const int b_ = bh >> 4, h_ = bh & 15;
  const char* KsB = (const char*)&Ks[0][0];
  const char* VsB = (const char*)&Vs[0][0];

  for (int pass = 0; pass < 2; ++pass) {
    const int qt = pass ? j_ : 7 - j_;
    const int qrow = qt * 256 + w * 32 + q5;
    bf16x8 qf[4];   // Q^T B-operand, chunk c: d = 16c+8*hi2+(0..7); scaled
#pragma unroll
    for (int c = 0; c < 4; c++) {
      bf16x8 rq = *(const bf16x8*)&qb[(size_t)qrow * 64 + 16 * c + 8 * hi2];
      bf16x8 s_;
#pragma unroll
      for (int j2 = 0; j2 < 8; j2++)
        s_[j2] = (bf16)((float)rq[j2] * 0.18033688011112042f);
      qf[c] = s_;
    }

    f32x16 acc[2] = {};
    float l_r = 0.f;
    const int nkv = 4 * qt + 4;
    const int qmaxw = qt * 256 + w * 32 + 31;   // max q row of this wave

    int cur = 0, nxt = 1, ovr = 2;
    stage(0, 0);
    stage(1, 1);
#pragma unroll 1
    for (int nt = 0; nt < nkv; ++nt) {
      if (nt + 2 < nkv) {
        stage(nt + 2, ovr);
        asm volatile("s_waitcnt vmcnt(4)" ::: "memory");
      } else if (nt + 1 < nkv) {
        asm volatile("s_waitcnt vmcnt(2)" ::: "memory");
      } else {
        asm volatile("s_waitcnt vmcnt(0)" ::: "memory");
      }
      __builtin_amdgcn_s_barrier();
      __builtin_amdgcn_sched_barrier(0);

      const bool live = (64 * nt) <= qmaxw;
      if (live) {
        const int bo = cur * 8192;

        // S^T = K Q^T: half-tile T (kv 32T..+31), chain over c (d = 16c..)
        f32x16 sc[2] = {};
        __builtin_amdgcn_s_setprio(1);
#pragma unroll
        for (int c = 0; c < 4; c++) {
#pragma unroll
          for (int T = 0; T < 2; T++) {
            bf16x8 kf = *(const bf16x8*)(KsB + bo + T * 4096 + kaddr[c]);
            sc[T] = __builtin_amdgcn_mfma_f32_32x32x16_bf16(kf, qf[c], sc[T], 0, 0, 0);
          }
        }
        __builtin_amdgcn_s_setprio(0);

        if (64 * nt + 63 > qt * 256 + w * 32) {   // diagonal: causal mask
#pragma unroll
          for (int T = 0; T < 2; T++)
#pragma unroll
            for (int r = 0; r < 16; r++) {
              int kvg = 64 * nt + 32 * T + (r & 3) + 8 * (r >> 2) + 4 * hi2;
              if (kvg > qrow) sc[T][r] = -1e30f;
            }
        }

        // softmax (no max-subtract): P' = exp2(sc); row-sum in-lane + xor32
        float rs = 0.f;
#pragma unroll
        for (int T = 0; T < 2; T++)
#pragma unroll
          for (int r = 0; r < 16; r++) {
            float pv = __builtin_amdgcn_exp2f(sc[T][r]);
            sc[T][r] = pv;
            rs += pv;
          }
        rs += __shfl_xor(rs, 32);
        l_r += rs;

        // pack P: A-frag(c) = sc[c>>1] regs 8*(c&1)..+7 natural order (sigma)
        bf16x8 pa[4];
#pragma unroll
        for (int c = 0; c < 4; c++)
#pragma unroll
          for (int j2 = 0; j2 < 8; j2++)
            pa[c][j2] = (bf16)sc[c >> 1][8 * (c & 1) + j2];

        // O += P'V: B-frag(c,dt) = V[sigma(16c+8hi2+j)][32dt+q5], 2x b64
        __builtin_amdgcn_s_setprio(1);
#pragma unroll
        for (int c = 0; c < 4; c++) {
#pragma unroll
          for (int dt = 0; dt < 2; dt++) {
            bf16x4 v0 = *(const bf16x4*)(VsB + bo + dt * 4096 + vaddr[2 * c]);
            bf16x4 v1 = *(const bf16x4*)(VsB + bo + dt * 4096 + vaddr[2 * c + 1]);
            bf16x8 bv;
#pragma unroll
            for (int j2 = 0; j2 < 4; j2++) { bv[j2] = v0[j2]; bv[4 + j2] = v1[j2]; }
            acc[dt] = __builtin_amdgcn_mfma_f32_32x32x16_bf16(pa[c], bv, acc[dt], 0, 0, 0);
          }
        }
        __builtin_amdgcn_s_setprio(0);
      }

      asm volatile("s_waitcnt lgkmcnt(0)" ::: "memory");
      __builtin_amdgcn_sched_barrier(0);
      __builtin_amdgcn_s_barrier();
      int t3 = cur; cur = nxt; nxt = ovr; ovr = t3;
    }

    // epilogue: O row = qt*256 + w*32 + rmap(r,hi2), col d = 32dt + q5
    float linv = 1.f / l_r;
#pragma unroll
    for (int r = 0; r < 16; r++) {
      int rmap = (r & 3) + 8 * (r >> 2) + 4 * hi2;
      float li = __shfl(linv, rmap);
      int rowq = qt * 256 + w * 32 + rmap;
      size_t rb = ((size_t)(b_ * S + rowq) << 10) + h_ * 64 + q5;
#pragma unroll
      for (int dt = 0; dt < 2; dt++)
        att[rb + 32 * dt] = (bf16)(acc[dt][r] * li);
    }
  }
}

extern "C" void kernel_launch(void* const* d_in, const int* in_sizes, int n_in,
                              void* d_out, int out_size, void* d_ws, size_t ws_size,
                              hipStream_t stream) {
  const float* x  = (const float*)d_in[0];
  const int* tp   = (const int*)d_in[1];
  const float* wq = (const float*)d_in[2];
  const float* wk = (const float*)d_in[3];
  const float* wv = (const float*)d_in[4];
  const float* wo = (const float*)d_in[5];
  float* out = (float*)d_out;

  char* ws = (char*)d_ws;
  const size_t TEN = 16777216;  // 8192*1024*2 bytes
  bf16* x_bf    = (bf16*)(ws);
  bf16* q_bf    = (bf16*)(ws + TEN);
  bf16* k_bf    = (bf16*)(ws + 2 * TEN);
  bf16* v_bf    = (bf16*)(ws + 3 * TEN);
  bf16* wqkv_bf = (bf16*)(ws + 4 * TEN);          // 3072x1024 = 6MB
  bf16* wo_bf   = wqkv_bf + 3 * 1048576;          // 2MB
  bf16* att_bf  = x_bf;   // alias: x_bf dead after QKV projection

  cvt_all<<<6144, 256, 0, stream>>>(x, wq, wk, wv, wo, x_bf, wqkv_bf, wo_bf);

  dim3 gq(32, 24);
  gemm_nt<3><<<gq, 512, 0, stream>>>(x_bf, wqkv_bf, q_bf, k_bf, v_bf, nullptr);

  rope2_k<<<8192, 256, 0, stream>>>(q_bf, k_bf, tp);

  dim3 ga(4, 64);
  attn_k<<<ga, 512, 0, stream>>>(q_bf, k_bf, v_bf, att_bf);

  dim3 go(32, 8);
  gemm_nt<2><<<go, 512, 0, stream>>>(att_bf, wo_bf, nullptr, nullptr, nullptr, out);
}

// Round 7
// 169.474 us; speedup vs baseline: 1.2986x; 1.1217x over previous
//
#include <hip/hip_runtime.h>
#include <hip/hip_bf16.h>
#include <stdint.h>

typedef __bf16 bf16;
typedef __bf16 bf16x4 __attribute__((ext_vector_type(4)));
typedef __bf16 bf16x8 __attribute__((ext_vector_type(8)));
typedef float f32x4 __attribute__((ext_vector_type(4)));
typedef float f32x16 __attribute__((ext_vector_type(16)));

#define GLDS16(g, l) __builtin_amdgcn_global_load_lds( \
    (const __attribute__((address_space(1))) void*)(g), \
    (__attribute__((address_space(3))) void*)(l), 16, 0, 0)

static constexpr int S = 2048;

// ---------------- fused f32 -> bf16 convert: x + 4 weights, 1 launch --------
__global__ __launch_bounds__(256) void cvt_all(const float* __restrict__ x,
                                               const float* __restrict__ wq,
                                               const float* __restrict__ wk,
                                               const float* __restrict__ wv,
                                               const float* __restrict__ wo,
                                               bf16* __restrict__ xb,
                                               bf16* __restrict__ wqkvb,
                                               bf16* __restrict__ wob) {
  const int bid = blockIdx.x;
  const float* src;
  bf16* dst;
  int i;
  if (bid < 4096) {            // x: 1,048,576 groups of 8
    src = x; dst = xb; i = bid * 256 + threadIdx.x;
  } else {                     // weights: 131,072 groups each
    int w = (bid - 4096) >> 9;
    i = ((bid - 4096) & 511) * 256 + threadIdx.x;
    src = (w == 0) ? wq : (w == 1) ? wk : (w == 2) ? wv : wo;
    dst = (w == 3) ? wob : wqkvb + (size_t)w * 1048576;
  }
  const float4* p = (const float4*)src + (size_t)i * 2;
  float4 a = p[0], b = p[1];
  bf16x8 o;
  o[0] = (bf16)a.x; o[1] = (bf16)a.y; o[2] = (bf16)a.z; o[3] = (bf16)a.w;
  o[4] = (bf16)b.x; o[5] = (bf16)b.y; o[6] = (bf16)b.z; o[7] = (bf16)b.w;
  *((bf16x8*)dst + i) = o;
}

// ---------------- NT GEMM, 128x128 tile, BK=64, 2 blocks/CU -----------------
// MODE 0 (QKV, 1536 blocks): wg<512 -> q, <1024 -> k (fused RoPE, LDS-coalesced
//   stores to [b,h,s,64]); wg>=1024 -> v computed as W.x^T so C rows = dd,
//   cols = s -> natural [b,h,dd,s] with coalesced row stores.
// MODE 2 (wo, 512 blocks): f32 direct stores to [m][1024].
// Double-buffered LDS ring (64 KB) + counted vmcnt(8); rows XOR-chunk-swizzled
// (conflict-free ds_read_b128); 65 KB LDS total -> 2 blocks/CU overlap.
template <int MODE>
__global__ __launch_bounds__(256, 2) void gemm_k(const bf16* __restrict__ xA,
                                                 const bf16* __restrict__ wB,
                                                 const int* __restrict__ tp,
                                                 bf16* __restrict__ oq,
                                                 bf16* __restrict__ ok,
                                                 bf16* __restrict__ ov,
                                                 float* __restrict__ outf) {
  constexpr int K = 1024;
  __shared__ __align__(16) char lds[65536];
  const int t = threadIdx.x, l = t & 63, wid = t >> 6;
  const int wm = wid >> 1, wn = wid & 1;

  // ---- block decode (XCD-bijective swizzle)
  int sel, tA, tB;
  const bf16 *Ap, *Bp;
  const int raw = blockIdx.x;
  if (MODE == 0) {
    int wg = (raw & 7) * 192 + (raw >> 3);          // 1536 = 8*192
    if (wg < 1024) {
      sel = wg >> 9;                                 // 0=q, 1=k
      int r2 = wg & 511;
      tB = r2 >> 6;                                  // col-tile 0..7
      tA = r2 & 63;                                  // s-tile 0..63
      Ap = xA + (size_t)tA * 128 * K;
      Bp = wB + (size_t)(sel * 1024 + tB * 128) * K;
    } else {
      sel = 2;
      int r2 = wg - 1024;
      tA = r2 >> 6;                                  // dd-tile 0..7
      tB = r2 & 63;                                  // s-tile 0..63
      Ap = wB + (size_t)(2048 + tA * 128) * K;       // A = wv rows (dd)
      Bp = xA + (size_t)tB * 128 * K;                // B = x rows (s)
    }
  } else {
    int wg = (raw & 7) * 64 + (raw >> 3);            // 512 = 8*64
    sel = 3;
    tA = wg >> 3; tB = wg & 7;
    Ap = xA + (size_t)tA * 128 * K;
    Bp = wB + (size_t)tB * 128 * K;
  }

  // ---- staging: wave stages 32 A-rows + 32 B-rows per K-tile (8 GLDS16)
  const int lrow = l >> 3;
  const int cswz = ((l & 7) ^ (lrow & 7)) * 8;       // pre-swizzled src chunk
  const bf16* aS = Ap + (size_t)(wid * 32 + lrow) * K + cswz;
  const bf16* bS = Bp + (size_t)(wid * 32 + lrow) * K + cswz;

  auto stage = [&](int kt, int buf) {
    char* base = lds + buf * 32768;
#pragma unroll
    for (int g = 0; g < 4; g++)
      GLDS16(aS + (size_t)(8 * g) * K + kt, base + (wid * 32 + 8 * g) * 128);
#pragma unroll
    for (int g = 0; g < 4; g++)
      GLDS16(bS + (size_t)(8 * g) * K + kt,
             base + 16384 + (wid * 32 + 8 * g) * 128);
  };

  // ---- loop-invariant LDS read offsets (chunk ^ (row&7) swizzle)
  int offA[4][2], offB[4][2];
#pragma unroll
  for (int f = 0; f < 4; f++)
#pragma unroll
    for (int kk = 0; kk < 2; kk++) {
      int ra = wm * 64 + f * 16 + (l & 15);
      offA[f][kk] = ra * 128 + (((kk * 4 + (l >> 4)) ^ (ra & 7)) * 16);
      int rb = wn * 64 + f * 16 + (l & 15);
      offB[f][kk] = 16384 + rb * 128 + (((kk * 4 + (l >> 4)) ^ (rb & 7)) * 16);
    }

  f32x4 acc[4][4] = {};

  stage(0, 0);
#pragma unroll 1
  for (int t_ = 0; t_ < 16; ++t_) {
    if (t_ < 15) {
      stage((t_ + 1) * 64, (t_ + 1) & 1);
      asm volatile("s_waitcnt vmcnt(8)" ::: "memory");
    } else {
      asm volatile("s_waitcnt vmcnt(0)" ::: "memory");
    }
    __builtin_amdgcn_s_barrier();
    __builtin_amdgcn_sched_barrier(0);

    const char* base = lds + (t_ & 1) * 32768;
    bf16x8 af[4][2], bg[4][2];
#pragma unroll
    for (int f = 0; f < 4; f++)
#pragma unroll
      for (int kk = 0; kk < 2; kk++) {
        af[f][kk] = *(const bf16x8*)(base + offA[f][kk]);
        bg[f][kk] = *(const bf16x8*)(base + offB[f][kk]);
      }
    __builtin_amdgcn_s_setprio(1);
#pragma unroll
    for (int mi = 0; mi < 4; mi++)
#pragma unroll
      for (int ni = 0; ni < 4; ni++)
#pragma unroll
        for (int kk = 0; kk < 2; kk++)
          acc[mi][ni] = __builtin_amdgcn_mfma_f32_16x16x32_bf16(
              af[mi][kk], bg[ni][kk], acc[mi][ni], 0, 0, 0);
    __builtin_amdgcn_s_setprio(0);
    asm volatile("s_waitcnt lgkmcnt(0)" ::: "memory");
    __builtin_amdgcn_sched_barrier(0);
    __builtin_amdgcn_s_barrier();
  }

  if (MODE == 2) {   // wo: direct f32 stores (64 B segments, full lines)
    const int rbase = tA * 128 + wm * 64 + (l >> 4) * 4;
    const int cbase = tB * 128 + wn * 64 + (l & 15);
#pragma unroll
    for (int mi = 0; mi < 4; mi++)
#pragma unroll
      for (int ni = 0; ni < 4; ni++)
#pragma unroll
        for (int r = 0; r < 4; r++)
          outf[(size_t)(rbase + mi * 16 + r) * 1024 + cbase + ni * 16] =
              acc[mi][ni][r];
    return;
  }

  // ---- E1: acc -> LDS [128][136] bf16 (ring is dead; overlay)
#pragma unroll
  for (int mi = 0; mi < 4; mi++)
#pragma unroll
    for (int ni = 0; ni < 4; ni++)
#pragma unroll
      for (int r = 0; r < 4; r++) {
        int row = wm * 64 + mi * 16 + (l >> 4) * 4 + r;
        int col = wn * 64 + ni * 16 + (l & 15);
        *(bf16*)(lds + row * 272 + col * 2) = (bf16)acc[mi][ni][r];
      }
  __syncthreads();

  // ---- E2: coalesced stores; 16 lanes cover one row (2x128B or 1x256B runs)
#pragma unroll 1
  for (int i = 0; i < 8; ++i) {
    const int id = t + 256 * i;
    const int row = id >> 4, ch = id & 15;
    bf16x8 v8 = *(const bf16x8*)(lds + row * 272 + ch * 16);
    if (sel < 2) {
      // q/k with fused RoPE: out row s = tA*128+row, head = tB*2+(ch>>3)
      const int m = tA * 128 + row;
      const float p = (float)tp[m];
      const int g = ch & 7;
      bf16x8 o;
#pragma unroll
      for (int j = 0; j < 4; j++) {
        float ang = p * exp2f((float)(g * 4 + j) * -0.4152410118609203f);
        float sn, cs;
        sincosf(ang, &sn, &cs);
        float e = (float)v8[2 * j], od = (float)v8[2 * j + 1];
        o[2 * j]     = (bf16)(e * cs - od * sn);
        o[2 * j + 1] = (bf16)(e * sn + od * cs);
      }
      bf16* dst = (sel == 0) ? oq : ok;
      const int h = tB * 2 + (ch >> 3);
      size_t idx = ((size_t)((m >> 11) * 16 + h) << 17) +
                   ((size_t)(m & 2047) << 6) + g * 8;
      *(bf16x8*)(dst + idx) = o;
    } else {
      // v: C row = dd (tA*128+row), cols = s (tB*128 + ch*8 ..)
      const int dd = tA * 128 + row;
      const int h = dd >> 6;
      const int s0 = tB * 128 + ch * 8;
      size_t idx = ((size_t)((s0 >> 11) * 16 + h) << 17) +
                   ((size_t)(dd & 63) << 11) + (s0 & 2047);
      *(bf16x8*)(ov + idx) = v8;
    }
  }
}

// ---------------- causal flash attention, 32x32x16, 8-wave QBLK=256 ---------
// grid (4, B*H), 512 thr = 8 waves, each wave owns 32 q rows (QBLK=256).
// Block j does q-tiles {7-j, j} -> uniform 36 kv-tiles. KVBLK=64.
// 3-deep circular K/V prefetch (vmcnt(4)): tile data issued 2 bodies ahead.
// Swapped QK^T: lane owns q-col q5; PV uses sigma=swap(bit2<->bit3) on kv so
// P-A-frag is the natural sc register packing (no cross-lane, no LDS for P).
// No max-subtract: P' = exp2(sc) (scores bounded ~13), scale cancels in O/l.
__global__ __launch_bounds__(512) void attn_k(const bf16* __restrict__ q,
                                              const bf16* __restrict__ k,
                                              const bf16* __restrict__ vt,
                                              bf16* __restrict__ att) {
  __shared__ bf16 Ks[3][4096];   // [buf][kv 64][d 64], rows XOR-swizzled
  __shared__ bf16 Vs[3][4096];   // [buf][d 64][kv 64], rows XOR-swizzled

  const int t = threadIdx.x, l = t & 63, w = t >> 6;   // w = 0..7
  const int hi2 = l >> 5, q5 = l & 31;

  const int raw = blockIdx.y * 4 + blockIdx.x;   // 0..255
  const int wg = (raw & 7) * 32 + (raw >> 3);    // XCD-bijective: 8 bh per XCD
  const int j_ = wg & 3;
  const int bh = wg >> 2;

  const bf16* qb = q + (size_t)bh * S * 64;
  const bf16* kb = k + (size_t)bh * S * 64;
  const bf16* vb = vt + (size_t)bh * 64 * S;

  // staging: wave w covers rows 8w..8w+7; lane l -> row 8w+(l>>3), chunk l&7
  const int lrow = l >> 3;
  const int clog = ((l & 7) ^ (lrow & 7)) * 8;   // pre-swizzled source chunk

  auto stage = [&](int nt, int b) {
    GLDS16(kb + (size_t)(nt * 64 + w * 8 + lrow) * 64 + clog, &Ks[b][w * 512]);
    GLDS16(vb + (size_t)(w * 8 + lrow) * S + nt * 64 + clog, &Vs[b][w * 512]);
  };

  // precomputed LDS byte offsets (loop-invariant, within one 8192B buffer)
  const int swz = (q5 & 7) << 4;
  int kaddr[4], vaddr[8];
#pragma unroll
  for (int c = 0; c < 4; c++)
    kaddr[c] = q5 * 128 + ((32 * c + 16 * hi2) ^ swz);
#pragma unroll
  for (int m = 0; m < 8; m++)
    vaddr[m] = q5 * 128 + ((16 * m) ^ swz) + 8 * hi2;

  const int b_ = bh >> 4, h_ = bh & 15;
  const char* KsB = (const char*)&Ks[0][0];
  const char* VsB = (const char*)&Vs[0][0];

  for (int pass = 0; pass < 2; ++pass) {
    const int qt = pass ? j_ : 7 - j_;
    const int qrow = qt * 256 + w * 32 + q5;
    bf16x8 qf[4];   // Q^T B-operand, chunk c: d = 16c+8*hi2+(0..7); scaled
#pragma unroll
    for (int c = 0; c < 4; c++) {
      bf16x8 rq = *(const bf16x8*)&qb[(size_t)qrow * 64 + 16 * c + 8 * hi2];
      bf16x8 s_;
#pragma unroll
      for (int j2 = 0; j2 < 8; j2++)
        s_[j2] = (bf16)((float)rq[j2] * 0.18033688011112042f);
      qf[c] = s_;
    }

    f32x16 acc[2] = {};
    float l_r = 0.f;
    const int nkv = 4 * qt + 4;
    const int qmaxw = qt * 256 + w * 32 + 31;   // max q row of this wave

    int cur = 0, nxt = 1, ovr = 2;
    stage(0, 0);
    stage(1, 1);
#pragma unroll 1
    for (int nt = 0; nt < nkv; ++nt) {
      if (nt + 2 < nkv) {
        stage(nt + 2, ovr);
        asm volatile("s_waitcnt vmcnt(4)" ::: "memory");
      } else if (nt + 1 < nkv) {
        asm volatile("s_waitcnt vmcnt(2)" ::: "memory");
      } else {
        asm volatile("s_waitcnt vmcnt(0)" ::: "memory");
      }
      __builtin_amdgcn_s_barrier();
      __builtin_amdgcn_sched_barrier(0);

      const bool live = (64 * nt) <= qmaxw;
      if (live) {
        const int bo = cur * 8192;

        // S^T = K Q^T: half-tile T (kv 32T..+31), chain over c (d = 16c..)
        f32x16 sc[2] = {};
        __builtin_amdgcn_s_setprio(1);
#pragma unroll
        for (int c = 0; c < 4; c++) {
#pragma unroll
          for (int T = 0; T < 2; T++) {
            bf16x8 kf = *(const bf16x8*)(KsB + bo + T * 4096 + kaddr[c]);
            sc[T] = __builtin_amdgcn_mfma_f32_32x32x16_bf16(kf, qf[c], sc[T], 0, 0, 0);
          }
        }
        __builtin_amdgcn_s_setprio(0);

        if (64 * nt + 63 > qt * 256 + w * 32) {   // diagonal: causal mask
#pragma unroll
          for (int T = 0; T < 2; T++)
#pragma unroll
            for (int r = 0; r < 16; r++) {
              int kvg = 64 * nt + 32 * T + (r & 3) + 8 * (r >> 2) + 4 * hi2;
              if (kvg > qrow) sc[T][r] = -1e30f;
            }
        }

        // softmax (no max-subtract): P' = exp2(sc); row-sum in-lane + xor32
        float rs = 0.f;
#pragma unroll
        for (int T = 0; T < 2; T++)
#pragma unroll
          for (int r = 0; r < 16; r++) {
            float pv = __builtin_amdgcn_exp2f(sc[T][r]);
            sc[T][r] = pv;
            rs += pv;
          }
        rs += __shfl_xor(rs, 32);
        l_r += rs;

        // pack P: A-frag(c) = sc[c>>1] regs 8*(c&1)..+7 natural order (sigma)
        bf16x8 pa[4];
#pragma unroll
        for (int c = 0; c < 4; c++)
#pragma unroll
          for (int j2 = 0; j2 < 8; j2++)
            pa[c][j2] = (bf16)sc[c >> 1][8 * (c & 1) + j2];

        // O += P'V: B-frag(c,dt) = V[sigma(16c+8hi2+j)][32dt+q5], 2x b64
        __builtin_amdgcn_s_setprio(1);
#pragma unroll
        for (int c = 0; c < 4; c++) {
#pragma unroll
          for (int dt = 0; dt < 2; dt++) {
            bf16x4 v0 = *(const bf16x4*)(VsB + bo + dt * 4096 + vaddr[2 * c]);
            bf16x4 v1 = *(const bf16x4*)(VsB + bo + dt * 4096 + vaddr[2 * c + 1]);
            bf16x8 bv;
#pragma unroll
            for (int j2 = 0; j2 < 4; j2++) { bv[j2] = v0[j2]; bv[4 + j2] = v1[j2]; }
            acc[dt] = __builtin_amdgcn_mfma_f32_32x32x16_bf16(pa[c], bv, acc[dt], 0, 0, 0);
          }
        }
        __builtin_amdgcn_s_setprio(0);
      }

      asm volatile("s_waitcnt lgkmcnt(0)" ::: "memory");
      __builtin_amdgcn_sched_barrier(0);
      __builtin_amdgcn_s_barrier();
      int t3 = cur; cur = nxt; nxt = ovr; ovr = t3;
    }

    // epilogue: O row = qt*256 + w*32 + rmap(r,hi2), col d = 32dt + q5
    float linv = 1.f / l_r;
#pragma unroll
    for (int r = 0; r < 16; r++) {
      int rmap = (r & 3) + 8 * (r >> 2) + 4 * hi2;
      float li = __shfl(linv, rmap);
      int rowq = qt * 256 + w * 32 + rmap;
      size_t rb = ((size_t)(b_ * S + rowq) << 10) + h_ * 64 + q5;
#pragma unroll
      for (int dt = 0; dt < 2; dt++)
        att[rb + 32 * dt] = (bf16)(acc[dt][r] * li);
    }
  }
}

extern "C" void kernel_launch(void* const* d_in, const int* in_sizes, int n_in,
                              void* d_out, int out_size, void* d_ws, size_t ws_size,
                              hipStream_t stream) {
  const float* x  = (const float*)d_in[0];
  const int* tp   = (const int*)d_in[1];
  const float* wq = (const float*)d_in[2];
  const float* wk = (const float*)d_in[3];
  const float* wv = (const float*)d_in[4];
  const float* wo = (const float*)d_in[5];
  float* out = (float*)d_out;

  char* ws = (char*)d_ws;
  const size_t TEN = 16777216;  // 8192*1024*2 bytes
  bf16* x_bf    = (bf16*)(ws);
  bf16* q_bf    = (bf16*)(ws + TEN);
  bf16* k_bf    = (bf16*)(ws + 2 * TEN);
  bf16* v_bf    = (bf16*)(ws + 3 * TEN);
  bf16* wqkv_bf = (bf16*)(ws + 4 * TEN);          // 3072x1024 = 6MB
  bf16* wo_bf   = wqkv_bf + 3 * 1048576;          // 2MB
  bf16* att_bf  = x_bf;   // alias: x_bf dead after QKV projection

  cvt_all<<<6144, 256, 0, stream>>>(x, wq, wk, wv, wo, x_bf, wqkv_bf, wo_bf);

  gemm_k<0><<<1536, 256, 0, stream>>>(x_bf, wqkv_bf, tp, q_bf, k_bf, v_bf,
                                      nullptr);

  dim3 ga(4, 64);
  attn_k<<<ga, 512, 0, stream>>>(q_bf, k_bf, v_bf, att_bf);

  gemm_k<2><<<512, 256, 0, stream>>>(att_bf, wo_bf, nullptr, nullptr, nullptr,
                                     nullptr, out);
}

// Round 8
// 159.999 us; speedup vs baseline: 1.3755x; 1.0592x over previous
//
#include <hip/hip_runtime.h>
#include <hip/hip_bf16.h>
#include <stdint.h>

typedef __bf16 bf16;
typedef __bf16 bf16x4 __attribute__((ext_vector_type(4)));
typedef __bf16 bf16x8 __attribute__((ext_vector_type(8)));
typedef float f32x4 __attribute__((ext_vector_type(4)));
typedef float f32x16 __attribute__((ext_vector_type(16)));

#define GLDS16(g, l) __builtin_amdgcn_global_load_lds( \
    (const __attribute__((address_space(1))) void*)(g), \
    (__attribute__((address_space(3))) void*)(l), 16, 0, 0)

static constexpr int S = 2048;

// ---------------- fused f32 -> bf16 convert: x + 4 weights, 1 launch --------
__global__ __launch_bounds__(256) void cvt_all(const float* __restrict__ x,
                                               const float* __restrict__ wq,
                                               const float* __restrict__ wk,
                                               const float* __restrict__ wv,
                                               const float* __restrict__ wo,
                                               bf16* __restrict__ xb,
                                               bf16* __restrict__ wqkvb,
                                               bf16* __restrict__ wob) {
  const int bid = blockIdx.x;
  const float* src;
  bf16* dst;
  int i;
  if (bid < 4096) {            // x: 1,048,576 groups of 8
    src = x; dst = xb; i = bid * 256 + threadIdx.x;
  } else {                     // weights: 131,072 groups each
    int w = (bid - 4096) >> 9;
    i = ((bid - 4096) & 511) * 256 + threadIdx.x;
    src = (w == 0) ? wq : (w == 1) ? wk : (w == 2) ? wv : wo;
    dst = (w == 3) ? wob : wqkvb + (size_t)w * 1048576;
  }
  const float4* p = (const float4*)src + (size_t)i * 2;
  float4 a = p[0], b = p[1];
  bf16x8 o;
  o[0] = (bf16)a.x; o[1] = (bf16)a.y; o[2] = (bf16)a.z; o[3] = (bf16)a.w;
  o[4] = (bf16)b.x; o[5] = (bf16)b.y; o[6] = (bf16)b.z; o[7] = (bf16)b.w;
  *((bf16x8*)dst + i) = o;
}

// ---------------- NT GEMM, 128x128 tile, BK=32, 3 blocks/CU -----------------
// 3-buffer LDS ring (48 KB) + counted vmcnt(8) -> tile t issued at step t-2
// (2 K-steps of latency slack). chunk^((row>>1)&3) swizzle: 2-way-max bank
// aliasing (free) on ds_read_b128, pre-applied to the global source.
// 2D grid, natural dispatch: id = bm + 64*bn -> XCD = bm%8, so concurrent
// blocks sharing x[bm] co-locate on one XCD's L2.
// MODE 0 (QKV, grid 64x24): bn<8 q, bn<16 k (fused RoPE, LDS-bounce coalesced
//   stores); bn>=16 v computed as W.x^T -> [b,h,dd,s] with coalesced rows.
// MODE 2 (wo, grid 64x8): f32 direct stores to [m][1024].
template <int MODE>
__global__ __launch_bounds__(256, 3) void gemm_k(const bf16* __restrict__ xA,
                                                 const bf16* __restrict__ wB,
                                                 const int* __restrict__ tp,
                                                 bf16* __restrict__ oq,
                                                 bf16* __restrict__ ok,
                                                 bf16* __restrict__ ov,
                                                 float* __restrict__ outf) {
  constexpr int K = 1024;
  __shared__ __align__(16) char lds[49152];
  const int t = threadIdx.x, l = t & 63, wid = t >> 6;
  const int wm = wid >> 1, wn = wid & 1;
  const int bm = blockIdx.x, bn = blockIdx.y;

  // ---- block decode
  int sel, tA, tB;
  const bf16 *Ap, *Bp;
  if (MODE == 0) {
    if (bn < 16) {
      sel = bn >> 3;                                 // 0=q, 1=k
      tA = bm;                                       // s-tile 0..63
      tB = bn & 7;                                   // col-tile 0..7
      Ap = xA + (size_t)tA * 128 * K;
      Bp = wB + (size_t)(sel * 1024 + tB * 128) * K;
    } else {
      sel = 2;
      tA = bn - 16;                                  // dd-tile 0..7
      tB = bm;                                       // s-tile 0..63
      Ap = wB + (size_t)(2048 + tA * 128) * K;       // A = wv rows (dd)
      Bp = xA + (size_t)tB * 128 * K;                // B = x rows (s)
    }
  } else {
    sel = 3;
    tA = bm; tB = bn;
    Ap = xA + (size_t)tA * 128 * K;
    Bp = wB + (size_t)tB * 128 * K;
  }

  // ---- staging: 4 GLDS16/wave/step; lane l -> row l>>2, chunk l&3 (16B)
  // source chunk pre-swizzled by ((row>>1)&3) == ((l>>3)&3)
  const int lrow = l >> 2;
  const int csrc = ((l & 3) ^ ((l >> 3) & 3)) * 8;
  const bf16* aS = Ap + (size_t)(wid * 32 + lrow) * K + csrc;
  const bf16* bS = Bp + (size_t)(wid * 32 + lrow) * K + csrc;

  auto stage = [&](int kt, char* base) {
    GLDS16(aS + kt, base + (wid * 32) * 64);
    GLDS16(aS + (size_t)16 * K + kt, base + (wid * 32 + 16) * 64);
    GLDS16(bS + kt, base + 8192 + (wid * 32) * 64);
    GLDS16(bS + (size_t)16 * K + kt, base + 8192 + (wid * 32 + 16) * 64);
  };

  // ---- loop-invariant LDS read offsets: frag f; kc = l>>4
  int offA[4], offB[4];
#pragma unroll
  for (int f = 0; f < 4; f++) {
    int ra = wm * 64 + f * 16 + (l & 15);
    offA[f] = ra * 64 + (((l >> 4) ^ ((ra >> 1) & 3)) * 16);
    int rb = wn * 64 + f * 16 + (l & 15);
    offB[f] = 8192 + rb * 64 + (((l >> 4) ^ ((rb >> 1) & 3)) * 16);
  }

  f32x4 acc[4][4] = {};

  char* cur = lds;
  char* nxt = lds + 16384;
  char* ovr = lds + 32768;
  stage(0, cur);
  stage(32, nxt);
#pragma unroll 1
  for (int t_ = 0; t_ < 32; ++t_) {
    if (t_ + 2 < 32) {
      stage((t_ + 2) * 32, ovr);
      asm volatile("s_waitcnt vmcnt(8)" ::: "memory");
    } else if (t_ + 1 < 32) {
      asm volatile("s_waitcnt vmcnt(4)" ::: "memory");
    } else {
      asm volatile("s_waitcnt vmcnt(0)" ::: "memory");
    }
    __builtin_amdgcn_s_barrier();
    __builtin_amdgcn_sched_barrier(0);

    bf16x8 af[4], bg[4];
#pragma unroll
    for (int f = 0; f < 4; f++) {
      af[f] = *(const bf16x8*)(cur + offA[f]);
      bg[f] = *(const bf16x8*)(cur + offB[f]);
    }
    __builtin_amdgcn_s_setprio(1);
#pragma unroll
    for (int mi = 0; mi < 4; mi++)
#pragma unroll
      for (int ni = 0; ni < 4; ni++)
        acc[mi][ni] = __builtin_amdgcn_mfma_f32_16x16x32_bf16(
            af[mi], bg[ni], acc[mi][ni], 0, 0, 0);
    __builtin_amdgcn_s_setprio(0);
    asm volatile("s_waitcnt lgkmcnt(0)" ::: "memory");
    __builtin_amdgcn_sched_barrier(0);
    __builtin_amdgcn_s_barrier();
    char* tmp = cur; cur = nxt; nxt = ovr; ovr = tmp;
  }

  if (MODE == 2) {   // wo: direct f32 stores (64 B segments, full lines)
    const int rbase = tA * 128 + wm * 64 + (l >> 4) * 4;
    const int cbase = tB * 128 + wn * 64 + (l & 15);
#pragma unroll
    for (int mi = 0; mi < 4; mi++)
#pragma unroll
      for (int ni = 0; ni < 4; ni++)
#pragma unroll
        for (int r = 0; r < 4; r++)
          outf[(size_t)(rbase + mi * 16 + r) * 1024 + cbase + ni * 16] =
              acc[mi][ni][r];
    return;
  }

  // ---- E1: acc -> LDS [128][136] bf16 overlay (ring is dead)
#pragma unroll
  for (int mi = 0; mi < 4; mi++)
#pragma unroll
    for (int ni = 0; ni < 4; ni++)
#pragma unroll
      for (int r = 0; r < 4; r++) {
        int row = wm * 64 + mi * 16 + (l >> 4) * 4 + r;
        int col = wn * 64 + ni * 16 + (l & 15);
        *(bf16*)(lds + row * 272 + col * 2) = (bf16)acc[mi][ni][r];
      }
  __syncthreads();

  // ---- E2: coalesced stores; 16 lanes cover one row
#pragma unroll 1
  for (int i = 0; i < 8; ++i) {
    const int id = t + 256 * i;
    const int row = id >> 4, ch = id & 15;
    bf16x8 v8 = *(const bf16x8*)(lds + row * 272 + ch * 16);
    if (sel < 2) {
      // q/k with fused RoPE: out row s = tA*128+row, head = tB*2+(ch>>3)
      const int m = tA * 128 + row;
      const float p = (float)tp[m];
      const int g = ch & 7;
      bf16x8 o;
#pragma unroll
      for (int j = 0; j < 4; j++) {
        float ang = p * exp2f((float)(g * 4 + j) * -0.4152410118609203f);
        float sn, cs;
        sincosf(ang, &sn, &cs);
        float e = (float)v8[2 * j], od = (float)v8[2 * j + 1];
        o[2 * j]     = (bf16)(e * cs - od * sn);
        o[2 * j + 1] = (bf16)(e * sn + od * cs);
      }
      bf16* dst = (sel == 0) ? oq : ok;
      const int h = tB * 2 + (ch >> 3);
      size_t idx = ((size_t)((m >> 11) * 16 + h) << 17) +
                   ((size_t)(m & 2047) << 6) + g * 8;
      *(bf16x8*)(dst + idx) = o;
    } else {
      // v: C row = dd (tA*128+row), cols = s (tB*128 + ch*8 ..)
      const int dd = tA * 128 + row;
      const int h = dd >> 6;
      const int s0 = tB * 128 + ch * 8;
      size_t idx = ((size_t)((s0 >> 11) * 16 + h) << 17) +
                   ((size_t)(dd & 63) << 11) + (s0 & 2047);
      *(bf16x8*)(ov + idx) = v8;
    }
  }
}

// ---------------- causal flash attention, 32x32x16, 8-wave QBLK=256 ---------
// grid (4, B*H), 512 thr = 8 waves, each wave owns 32 q rows (QBLK=256).
// Block j does q-tiles {7-j, j} -> uniform 36 kv-tiles. KVBLK=64.
// 3-deep circular K/V prefetch (vmcnt(4)): tile data issued 2 bodies ahead.
// Swapped QK^T: lane owns q-col q5; PV uses sigma=swap(bit2<->bit3) on kv so
// P-A-frag is the natural sc register packing (no cross-lane, no LDS for P).
// No max-subtract: P' = exp2(sc) (scores bounded ~13), scale cancels in O/l.
__global__ __launch_bounds__(512) void attn_k(const bf16* __restrict__ q,
                                              const bf16* __restrict__ k,
                                              const bf16* __restrict__ vt,
                                              bf16* __restrict__ att) {
  __shared__ bf16 Ks[3][4096];   // [buf][kv 64][d 64], rows XOR-swizzled
  __shared__ bf16 Vs[3][4096];   // [buf][d 64][kv 64], rows XOR-swizzled

  const int t = threadIdx.x, l = t & 63, w = t >> 6;   // w = 0..7
  const int hi2 = l >> 5, q5 = l & 31;

  const int raw = blockIdx.y * 4 + blockIdx.x;   // 0..255
  const int wg = (raw & 7) * 32 + (raw >> 3);    // XCD-bijective: 8 bh per XCD
  const int j_ = wg & 3;
  const int bh = wg >> 2;

  const bf16* qb = q + (size_t)bh * S * 64;
  const bf16* kb = k + (size_t)bh * S * 64;
  const bf16* vb = vt + (size_t)bh * 64 * S;

  // staging: wave w covers rows 8w..8w+7; lane l -> row 8w+(l>>3), chunk l&7
  const int lrow = l >> 3;
  const int clog = ((l & 7) ^ (lrow & 7)) * 8;   // pre-swizzled source chunk

  auto stage = [&](int nt, int b) {
    GLDS16(kb + (size_t)(nt * 64 + w * 8 + lrow) * 64 + clog, &Ks[b][w * 512]);
    GLDS16(vb + (size_t)(w * 8 + lrow) * S + nt * 64 + clog, &Vs[b][w * 512]);
  };

  // precomputed LDS byte offsets (loop-invariant, within one 8192B buffer)
  const int swz = (q5 & 7) << 4;
  int kaddr[4], vaddr[8];
#pragma unroll
  for (int c = 0; c < 4; c++)
    kaddr[c] = q5 * 128 + ((32 * c + 16 * hi2) ^ swz);
#pragma unroll
  for (int m = 0; m < 8; m++)
    vaddr[m] = q5 * 128 + ((16 * m) ^ swz) + 8 * hi2;

  const int b_ = bh >> 4, h_ = bh & 15;
  const char* KsB = (const char*)&Ks[0][0];
  const char* VsB = (const char*)&Vs[0][0];

  for (int pass = 0; pass < 2; ++pass) {
    const int qt = pass ? j_ : 7 - j_;
    const int qrow = qt * 256 + w * 32 + q5;
    bf16x8 qf[4];   // Q^T B-operand, chunk c: d = 16c+8*hi2+(0..7); scaled
#pragma unroll
    for (int c = 0; c < 4; c++) {
      bf16x8 rq = *(const bf16x8*)&qb[(size_t)qrow * 64 + 16 * c + 8 * hi2];
      bf16x8 s_;
#pragma unroll
      for (int j2 = 0; j2 < 8; j2++)
        s_[j2] = (bf16)((float)rq[j2] * 0.18033688011112042f);
      qf[c] = s_;
    }

    f32x16 acc[2] = {};
    float l_r = 0.f;
    const int nkv = 4 * qt + 4;
    const int qmaxw = qt * 256 + w * 32 + 31;   // max q row of this wave

    int cur = 0, nxt = 1, ovr = 2;
    stage(0, 0);
    stage(1, 1);
#pragma unroll 1
    for (int nt = 0; nt < nkv; ++nt) {
      if (nt + 2 < nkv) {
        stage(nt + 2, ovr);
        asm volatile("s_waitcnt vmcnt(4)" ::: "memory");
      } else if (nt + 1 < nkv) {
        asm volatile("s_waitcnt vmcnt(2)" ::: "memory");
      } else {
        asm volatile("s_waitcnt vmcnt(0)" ::: "memory");
      }
      __builtin_amdgcn_s_barrier();
      __builtin_amdgcn_sched_barrier(0);

      const bool live = (64 * nt) <= qmaxw;
      if (live) {
        const int bo = cur * 8192;

        // S^T = K Q^T: half-tile T (kv 32T..+31), chain over c (d = 16c..)
        f32x16 sc[2] = {};
        __builtin_amdgcn_s_setprio(1);
#pragma unroll
        for (int c = 0; c < 4; c++) {
#pragma unroll
          for (int T = 0; T < 2; T++) {
            bf16x8 kf = *(const bf16x8*)(KsB + bo + T * 4096 + kaddr[c]);
            sc[T] = __builtin_amdgcn_mfma_f32_32x32x16_bf16(kf, qf[c], sc[T], 0, 0, 0);
          }
        }
        __builtin_amdgcn_s_setprio(0);

        if (64 * nt + 63 > qt * 256 + w * 32) {   // diagonal: causal mask
#pragma unroll
          for (int T = 0; T < 2; T++)
#pragma unroll
            for (int r = 0; r < 16; r++) {
              int kvg = 64 * nt + 32 * T + (r & 3) + 8 * (r >> 2) + 4 * hi2;
              if (kvg > qrow) sc[T][r] = -1e30f;
            }
        }

        // softmax (no max-subtract): P' = exp2(sc); row-sum in-lane + xor32
        float rs = 0.f;
#pragma unroll
        for (int T = 0; T < 2; T++)
#pragma unroll
          for (int r = 0; r < 16; r++) {
            float pv = __builtin_amdgcn_exp2f(sc[T][r]);
            sc[T][r] = pv;
            rs += pv;
          }
        rs += __shfl_xor(rs, 32);
        l_r += rs;

        // pack P: A-frag(c) = sc[c>>1] regs 8*(c&1)..+7 natural order (sigma)
        bf16x8 pa[4];
#pragma unroll
        for (int c = 0; c < 4; c++)
#pragma unroll
          for (int j2 = 0; j2 < 8; j2++)
            pa[c][j2] = (bf16)sc[c >> 1][8 * (c & 1) + j2];

        // O += P'V: B-frag(c,dt) = V[sigma(16c+8hi2+j)][32dt+q5], 2x b64
        __builtin_amdgcn_s_setprio(1);
#pragma unroll
        for (int c = 0; c < 4; c++) {
#pragma unroll
          for (int dt = 0; dt < 2; dt++) {
            bf16x4 v0 = *(const bf16x4*)(VsB + bo + dt * 4096 + vaddr[2 * c]);
            bf16x4 v1 = *(const bf16x4*)(VsB + bo + dt * 4096 + vaddr[2 * c + 1]);
            bf16x8 bv;
#pragma unroll
            for (int j2 = 0; j2 < 4; j2++) { bv[j2] = v0[j2]; bv[4 + j2] = v1[j2]; }
            acc[dt] = __builtin_amdgcn_mfma_f32_32x32x16_bf16(pa[c], bv, acc[dt], 0, 0, 0);
          }
        }
        __builtin_amdgcn_s_setprio(0);
      }

      asm volatile("s_waitcnt lgkmcnt(0)" ::: "memory");
      __builtin_amdgcn_sched_barrier(0);
      __builtin_amdgcn_s_barrier();
      int t3 = cur; cur = nxt; nxt = ovr; ovr = t3;
    }

    // epilogue: O row = qt*256 + w*32 + rmap(r,hi2), col d = 32dt + q5
    float linv = 1.f / l_r;
#pragma unroll
    for (int r = 0; r < 16; r++) {
      int rmap = (r & 3) + 8 * (r >> 2) + 4 * hi2;
      float li = __shfl(linv, rmap);
      int rowq = qt * 256 + w * 32 + rmap;
      size_t rb = ((size_t)(b_ * S + rowq) << 10) + h_ * 64 + q5;
#pragma unroll
      for (int dt = 0; dt < 2; dt++)
        att[rb + 32 * dt] = (bf16)(acc[dt][r] * li);
    }
  }
}

extern "C" void kernel_launch(void* const* d_in, const int* in_sizes, int n_in,
                              void* d_out, int out_size, void* d_ws, size_t ws_size,
                              hipStream_t stream) {
  const float* x  = (const float*)d_in[0];
  const int* tp   = (const int*)d_in[1];
  const float* wq = (const float*)d_in[2];
  const float* wk = (const float*)d_in[3];
  const float* wv = (const float*)d_in[4];
  const float* wo = (const float*)d_in[5];
  float* out = (float*)d_out;

  char* ws = (char*)d_ws;
  const size_t TEN = 16777216;  // 8192*1024*2 bytes
  bf16* x_bf    = (bf16*)(ws);
  bf16* q_bf    = (bf16*)(ws + TEN);
  bf16* k_bf    = (bf16*)(ws + 2 * TEN);
  bf16* v_bf    = (bf16*)(ws + 3 * TEN);
  bf16* wqkv_bf = (bf16*)(ws + 4 * TEN);          // 3072x1024 = 6MB
  bf16* wo_bf   = wqkv_bf + 3 * 1048576;          // 2MB
  bf16* att_bf  = x_bf;   // alias: x_bf dead after QKV projection

  cvt_all<<<6144, 256, 0, stream>>>(x, wq, wk, wv, wo, x_bf, wqkv_bf, wo_bf);

  dim3 gq(64, 24);
  gemm_k<0><<<gq, 256, 0, stream>>>(x_bf, wqkv_bf, tp, q_bf, k_bf, v_bf,
                                    nullptr);

  dim3 ga(4, 64);
  attn_k<<<ga, 512, 0, stream>>>(q_bf, k_bf, v_bf, att_bf);

  dim3 go(64, 8);
  gemm_k<2><<<go, 256, 0, stream>>>(att_bf, wo_bf, nullptr, nullptr, nullptr,
                                    nullptr, out);
}

// Round 9
// 154.399 us; speedup vs baseline: 1.4254x; 1.0363x over previous
//
#include <hip/hip_runtime.h>
#include <hip/hip_bf16.h>
#include <stdint.h>

typedef __bf16 bf16;
typedef __bf16 bf16x4 __attribute__((ext_vector_type(4)));
typedef __bf16 bf16x8 __attribute__((ext_vector_type(8)));
typedef float f32x4 __attribute__((ext_vector_type(4)));
typedef float f32x16 __attribute__((ext_vector_type(16)));

#define GLDS16(g, l) __builtin_amdgcn_global_load_lds( \
    (const __attribute__((address_space(1))) void*)(g), \
    (__attribute__((address_space(3))) void*)(l), 16, 0, 0)

static constexpr int S = 2048;

// ---- fused f32->bf16 convert (x + 4 weights) + RoPE cos/sin table build ----
__global__ __launch_bounds__(256) void cvt_all(const float* __restrict__ x,
                                               const float* __restrict__ wq,
                                               const float* __restrict__ wk,
                                               const float* __restrict__ wv,
                                               const float* __restrict__ wo,
                                               const int* __restrict__ tp,
                                               bf16* __restrict__ xb,
                                               bf16* __restrict__ wqkvb,
                                               bf16* __restrict__ wob,
                                               bf16* __restrict__ tabc,
                                               bf16* __restrict__ tabs) {
  const int bid = blockIdx.x;
  if (bid >= 6144) {   // RoPE table: 8192 rows x 32 pairs
    int idx = (bid - 6144) * 256 + threadIdx.x;   // 0..262143
    int row = idx >> 5, pp = idx & 31;
    float p = (float)tp[row];
    float ang = p * exp2f((float)pp * -0.4152410118609203f);
    float sn, cs;
    sincosf(ang, &sn, &cs);
    tabc[idx] = (bf16)cs;
    tabs[idx] = (bf16)sn;
    return;
  }
  const float* src;
  bf16* dst;
  int i;
  if (bid < 4096) {            // x: 1,048,576 groups of 8
    src = x; dst = xb; i = bid * 256 + threadIdx.x;
  } else {                     // weights: 131,072 groups each
    int w = (bid - 4096) >> 9;
    i = ((bid - 4096) & 511) * 256 + threadIdx.x;
    src = (w == 0) ? wq : (w == 1) ? wk : (w == 2) ? wv : wo;
    dst = (w == 3) ? wob : wqkvb + (size_t)w * 1048576;
  }
  const float4* p = (const float4*)src + (size_t)i * 2;
  float4 a = p[0], b = p[1];
  bf16x8 o;
  o[0] = (bf16)a.x; o[1] = (bf16)a.y; o[2] = (bf16)a.z; o[3] = (bf16)a.w;
  o[4] = (bf16)b.x; o[5] = (bf16)b.y; o[6] = (bf16)b.z; o[7] = (bf16)b.w;
  *((bf16x8*)dst + i) = o;
}

// ---------------- NT GEMM, 128x128 tile, BK=32, 3 blocks/CU -----------------
// 3-buffer LDS ring (48 KB) + counted vmcnt(8); chunk^((row>>1)&3) swizzle
// pre-applied to the global source (2-way-max bank aliasing on ds_read_b128).
// 2D grid natural dispatch: XCD = bm%8 -> blocks sharing x[bm] co-locate.
// MODE 0 (QKV, grid 64x24): bn<8 q, bn<16 k (table-RoPE, LDS-bounce coalesced
//   stores); bn>=16 v computed as W.x^T -> [b,h,dd,s] with coalesced rows.
// MODE 2 (wo, grid 64x8): f32 direct stores to [m][1024].
template <int MODE>
__global__ __launch_bounds__(256, 3) void gemm_k(const bf16* __restrict__ xA,
                                                 const bf16* __restrict__ wB,
                                                 const bf16* __restrict__ tabc,
                                                 const bf16* __restrict__ tabs,
                                                 bf16* __restrict__ oq,
                                                 bf16* __restrict__ ok,
                                                 bf16* __restrict__ ov,
                                                 float* __restrict__ outf) {
  constexpr int K = 1024;
  __shared__ __align__(16) char lds[49152];
  const int t = threadIdx.x, l = t & 63, wid = t >> 6;
  const int wm = wid >> 1, wn = wid & 1;
  const int bm = blockIdx.x, bn = blockIdx.y;

  // ---- block decode
  int sel, tA, tB;
  const bf16 *Ap, *Bp;
  if (MODE == 0) {
    if (bn < 16) {
      sel = bn >> 3;                                 // 0=q, 1=k
      tA = bm;                                       // s-tile 0..63
      tB = bn & 7;                                   // col-tile 0..7
      Ap = xA + (size_t)tA * 128 * K;
      Bp = wB + (size_t)(sel * 1024 + tB * 128) * K;
    } else {
      sel = 2;
      tA = bn - 16;                                  // dd-tile 0..7
      tB = bm;                                       // s-tile 0..63
      Ap = wB + (size_t)(2048 + tA * 128) * K;       // A = wv rows (dd)
      Bp = xA + (size_t)tB * 128 * K;                // B = x rows (s)
    }
  } else {
    sel = 3;
    tA = bm; tB = bn;
    Ap = xA + (size_t)tA * 128 * K;
    Bp = wB + (size_t)tB * 128 * K;
  }

  // ---- staging: 4 GLDS16/wave/step; lane l -> row l>>2, chunk l&3 (16B)
  const int lrow = l >> 2;
  const int csrc = ((l & 3) ^ ((l >> 3) & 3)) * 8;
  const bf16* aS = Ap + (size_t)(wid * 32 + lrow) * K + csrc;
  const bf16* bS = Bp + (size_t)(wid * 32 + lrow) * K + csrc;

  auto stage = [&](int kt, char* base) {
    GLDS16(aS + kt, base + (wid * 32) * 64);
    GLDS16(aS + (size_t)16 * K + kt, base + (wid * 32 + 16) * 64);
    GLDS16(bS + kt, base + 8192 + (wid * 32) * 64);
    GLDS16(bS + (size_t)16 * K + kt, base + 8192 + (wid * 32 + 16) * 64);
  };

  // ---- loop-invariant LDS read offsets
  int offA[4], offB[4];
#pragma unroll
  for (int f = 0; f < 4; f++) {
    int ra = wm * 64 + f * 16 + (l & 15);
    offA[f] = ra * 64 + (((l >> 4) ^ ((ra >> 1) & 3)) * 16);
    int rb = wn * 64 + f * 16 + (l & 15);
    offB[f] = 8192 + rb * 64 + (((l >> 4) ^ ((rb >> 1) & 3)) * 16);
  }

  f32x4 acc[4][4] = {};

  char* cur = lds;
  char* nxt = lds + 16384;
  char* ovr = lds + 32768;
  stage(0, cur);
  stage(32, nxt);
#pragma unroll 1
  for (int t_ = 0; t_ < 32; ++t_) {
    if (t_ + 2 < 32) {
      stage((t_ + 2) * 32, ovr);
      asm volatile("s_waitcnt vmcnt(8)" ::: "memory");
    } else if (t_ + 1 < 32) {
      asm volatile("s_waitcnt vmcnt(4)" ::: "memory");
    } else {
      asm volatile("s_waitcnt vmcnt(0)" ::: "memory");
    }
    __builtin_amdgcn_s_barrier();
    __builtin_amdgcn_sched_barrier(0);

    bf16x8 af[4], bg[4];
#pragma unroll
    for (int f = 0; f < 4; f++) {
      af[f] = *(const bf16x8*)(cur + offA[f]);
      bg[f] = *(const bf16x8*)(cur + offB[f]);
    }
    __builtin_amdgcn_s_setprio(1);
#pragma unroll
    for (int mi = 0; mi < 4; mi++)
#pragma unroll
      for (int ni = 0; ni < 4; ni++)
        acc[mi][ni] = __builtin_amdgcn_mfma_f32_16x16x32_bf16(
            af[mi], bg[ni], acc[mi][ni], 0, 0, 0);
    __builtin_amdgcn_s_setprio(0);
    asm volatile("s_waitcnt lgkmcnt(0)" ::: "memory");
    __builtin_amdgcn_sched_barrier(0);
    __builtin_amdgcn_s_barrier();
    char* tmp = cur; cur = nxt; nxt = ovr; ovr = tmp;
  }

  if (MODE == 2) {   // wo: direct f32 stores (64 B segments, full lines)
    const int rbase = tA * 128 + wm * 64 + (l >> 4) * 4;
    const int cbase = tB * 128 + wn * 64 + (l & 15);
#pragma unroll
    for (int mi = 0; mi < 4; mi++)
#pragma unroll
      for (int ni = 0; ni < 4; ni++)
#pragma unroll
        for (int r = 0; r < 4; r++)
          outf[(size_t)(rbase + mi * 16 + r) * 1024 + cbase + ni * 16] =
              acc[mi][ni][r];
    return;
  }

  // ---- E1: acc -> LDS [128][136] bf16 overlay (ring is dead)
#pragma unroll
  for (int mi = 0; mi < 4; mi++)
#pragma unroll
    for (int ni = 0; ni < 4; ni++)
#pragma unroll
      for (int r = 0; r < 4; r++) {
        int row = wm * 64 + mi * 16 + (l >> 4) * 4 + r;
        int col = wn * 64 + ni * 16 + (l & 15);
        *(bf16*)(lds + row * 272 + col * 2) = (bf16)acc[mi][ni][r];
      }
  __syncthreads();

  // ---- E2: coalesced stores; 16 lanes cover one row; RoPE via bf16 tables
#pragma unroll 2
  for (int i = 0; i < 8; ++i) {
    const int id = t + 256 * i;
    const int row = id >> 4, ch = id & 15;
    bf16x8 v8 = *(const bf16x8*)(lds + row * 272 + ch * 16);
    if (sel < 2) {
      const int m = tA * 128 + row;
      const int g = ch & 7;
      bf16x4 tc = *(const bf16x4*)(tabc + m * 32 + g * 4);
      bf16x4 tsn = *(const bf16x4*)(tabs + m * 32 + g * 4);
      bf16x8 o;
#pragma unroll
      for (int j = 0; j < 4; j++) {
        float cs = (float)tc[j], sn = (float)tsn[j];
        float e = (float)v8[2 * j], od = (float)v8[2 * j + 1];
        o[2 * j]     = (bf16)(e * cs - od * sn);
        o[2 * j + 1] = (bf16)(e * sn + od * cs);
      }
      bf16* dst = (sel == 0) ? oq : ok;
      const int h = tB * 2 + (ch >> 3);
      size_t idx = ((size_t)((m >> 11) * 16 + h) << 17) +
                   ((size_t)(m & 2047) << 6) + g * 8;
      *(bf16x8*)(dst + idx) = o;
    } else {
      const int dd = tA * 128 + row;
      const int h = dd >> 6;
      const int s0 = tB * 128 + ch * 8;
      size_t idx = ((size_t)((s0 >> 11) * 16 + h) << 17) +
                   ((size_t)(dd & 63) << 11) + (s0 & 2047);
      *(bf16x8*)(ov + idx) = v8;
    }
  }
}

// ---------------- causal flash attention, 32x32x16, 8-wave QBLK=256 ---------
// 512 blocks: one (bh, qt) each; raw<256 -> bh 0..31 qt=f, raw>=256 ->
// bh 32..63 qt=7-f (complementary pairing for 2-blocks/CU balance).
// Per-half (T=0,1) QK->softmax->PV restructure cuts live VGPRs; target
// <=128 VGPR via __launch_bounds__(512,4) -> 2 independent blocks/CU.
// 3-deep circular K/V prefetch; swapped QK^T; sigma-permuted in-register P;
// no max-subtract softmax (P' = exp2(sc), scale cancels in O/l).
__global__ __launch_bounds__(512, 4) void attn_k(const bf16* __restrict__ q,
                                                 const bf16* __restrict__ k,
                                                 const bf16* __restrict__ vt,
                                                 bf16* __restrict__ att) {
  __shared__ bf16 Ks[3][4096];   // [buf][kv 64][d 64], rows XOR-swizzled
  __shared__ bf16 Vs[3][4096];   // [buf][d 64][kv 64], rows XOR-swizzled

  const int t = threadIdx.x, l = t & 63, w = t >> 6;   // w = 0..7
  const int hi2 = l >> 5, q5 = l & 31;

  const int raw = blockIdx.x;
  const int r2 = raw & 255;
  const int wg = (r2 & 7) * 32 + (r2 >> 3);      // 4 bh per XCD, L2-local
  const int bh = ((raw < 256) ? 0 : 32) + (wg >> 3);
  const int qt = (raw < 256) ? (wg & 7) : 7 - (wg & 7);

  const bf16* qb = q + (size_t)bh * S * 64;
  const bf16* kb = k + (size_t)bh * S * 64;
  const bf16* vb = vt + (size_t)bh * 64 * S;

  const int lrow = l >> 3;
  const int clog = ((l & 7) ^ (lrow & 7)) * 8;   // pre-swizzled source chunk

  auto stage = [&](int nt, int b) {
    GLDS16(kb + (size_t)(nt * 64 + w * 8 + lrow) * 64 + clog, &Ks[b][w * 512]);
    GLDS16(vb + (size_t)(w * 8 + lrow) * S + nt * 64 + clog, &Vs[b][w * 512]);
  };

  const int swz = (q5 & 7) << 4;
  int kaddr[4], vaddr[8];
#pragma unroll
  for (int c = 0; c < 4; c++)
    kaddr[c] = q5 * 128 + ((32 * c + 16 * hi2) ^ swz);
#pragma unroll
  for (int m = 0; m < 8; m++)
    vaddr[m] = q5 * 128 + ((16 * m) ^ swz) + 8 * hi2;

  const int b_ = bh >> 4, h_ = bh & 15;
  const char* KsB = (const char*)&Ks[0][0];
  const char* VsB = (const char*)&Vs[0][0];

  const int wqbase = qt * 256 + w * 32;
  const int qrow = wqbase + q5;
  bf16x8 qf[4];   // Q^T B-operand, chunk c: d = 16c+8*hi2+(0..7); scaled
#pragma unroll
  for (int c = 0; c < 4; c++) {
    bf16x8 rq = *(const bf16x8*)&qb[(size_t)qrow * 64 + 16 * c + 8 * hi2];
    bf16x8 s_;
#pragma unroll
    for (int j2 = 0; j2 < 8; j2++)
      s_[j2] = (bf16)((float)rq[j2] * 0.18033688011112042f);
    qf[c] = s_;
  }

  f32x16 acc[2] = {};
  float l_r = 0.f;
  const int nkv = 4 * qt + 4;
  const int qmaxw = wqbase + 31;

  int cur = 0, nxt = 1, ovr = 2;
  stage(0, 0);
  stage(1, 1);
#pragma unroll 1
  for (int nt = 0; nt < nkv; ++nt) {
    if (nt + 2 < nkv) {
      stage(nt + 2, ovr);
      asm volatile("s_waitcnt vmcnt(4)" ::: "memory");
    } else if (nt + 1 < nkv) {
      asm volatile("s_waitcnt vmcnt(2)" ::: "memory");
    } else {
      asm volatile("s_waitcnt vmcnt(0)" ::: "memory");
    }
    __builtin_amdgcn_s_barrier();
    __builtin_amdgcn_sched_barrier(0);

    const bool live = (64 * nt) <= qmaxw;
    if (live) {
      const int bo = cur * 8192;
      float rs = 0.f;
#pragma unroll
      for (int T = 0; T < 2; T++) {
        // S^T = K Q^T for half-tile T (kv 32T..32T+31)
        f32x16 sc = {};
        __builtin_amdgcn_s_setprio(1);
#pragma unroll
        for (int c = 0; c < 4; c++) {
          bf16x8 kf = *(const bf16x8*)(KsB + bo + T * 4096 + kaddr[c]);
          sc = __builtin_amdgcn_mfma_f32_32x32x16_bf16(kf, qf[c], sc, 0, 0, 0);
        }
        __builtin_amdgcn_s_setprio(0);

        if (64 * nt + 32 * T + 31 > wqbase) {   // causal mask
#pragma unroll
          for (int r = 0; r < 16; r++) {
            int kvg = 64 * nt + 32 * T + (r & 3) + 8 * (r >> 2) + 4 * hi2;
            if (kvg > qrow) sc[r] = -1e30f;
          }
        }

        // softmax (no max-subtract) + pack P for this half
        bf16x8 pa0, pa1;
#pragma unroll
        for (int r = 0; r < 8; r++) {
          float p0 = __builtin_amdgcn_exp2f(sc[r]);
          float p1 = __builtin_amdgcn_exp2f(sc[8 + r]);
          rs += p0 + p1;
          pa0[r] = (bf16)p0;
          pa1[r] = (bf16)p1;
        }

        // O += P'V for this half: c = 2T (pa0), 2T+1 (pa1)
        __builtin_amdgcn_s_setprio(1);
#pragma unroll
        for (int dt = 0; dt < 2; dt++) {
          bf16x4 v0 = *(const bf16x4*)(VsB + bo + dt * 4096 + vaddr[4 * T]);
          bf16x4 v1 = *(const bf16x4*)(VsB + bo + dt * 4096 + vaddr[4 * T + 1]);
          bf16x8 bv;
#pragma unroll
          for (int j2 = 0; j2 < 4; j2++) { bv[j2] = v0[j2]; bv[4 + j2] = v1[j2]; }
          acc[dt] = __builtin_amdgcn_mfma_f32_32x32x16_bf16(pa0, bv, acc[dt], 0, 0, 0);
          v0 = *(const bf16x4*)(VsB + bo + dt * 4096 + vaddr[4 * T + 2]);
          v1 = *(const bf16x4*)(VsB + bo + dt * 4096 + vaddr[4 * T + 3]);
#pragma unroll
          for (int j2 = 0; j2 < 4; j2++) { bv[j2] = v0[j2]; bv[4 + j2] = v1[j2]; }
          acc[dt] = __builtin_amdgcn_mfma_f32_32x32x16_bf16(pa1, bv, acc[dt], 0, 0, 0);
        }
        __builtin_amdgcn_s_setprio(0);
      }
      rs += __shfl_xor(rs, 32);
      l_r += rs;
    }

    asm volatile("s_waitcnt lgkmcnt(0)" ::: "memory");
    __builtin_amdgcn_sched_barrier(0);
    __builtin_amdgcn_s_barrier();
    int t3 = cur; cur = nxt; nxt = ovr; ovr = t3;
  }

  // epilogue: O row = qt*256 + w*32 + rmap(r,hi2), col d = 32dt + q5
  float linv = 1.f / l_r;
#pragma unroll
  for (int r = 0; r < 16; r++) {
    int rmap = (r & 3) + 8 * (r >> 2) + 4 * hi2;
    float li = __shfl(linv, rmap);
    int rowq = wqbase + rmap;
    size_t rb = ((size_t)(b_ * S + rowq) << 10) + h_ * 64 + q5;
#pragma unroll
    for (int dt = 0; dt < 2; dt++)
      att[rb + 32 * dt] = (bf16)(acc[dt][r] * li);
  }
}

extern "C" void kernel_launch(void* const* d_in, const int* in_sizes, int n_in,
                              void* d_out, int out_size, void* d_ws, size_t ws_size,
                              hipStream_t stream) {
  const float* x  = (const float*)d_in[0];
  const int* tp   = (const int*)d_in[1];
  const float* wq = (const float*)d_in[2];
  const float* wk = (const float*)d_in[3];
  const float* wv = (const float*)d_in[4];
  const float* wo = (const float*)d_in[5];
  float* out = (float*)d_out;

  char* ws = (char*)d_ws;
  const size_t TEN = 16777216;  // 8192*1024*2 bytes
  bf16* x_bf    = (bf16*)(ws);
  bf16* q_bf    = (bf16*)(ws + TEN);
  bf16* k_bf    = (bf16*)(ws + 2 * TEN);
  bf16* v_bf    = (bf16*)(ws + 3 * TEN);
  bf16* wqkv_bf = (bf16*)(ws + 4 * TEN);          // 3072x1024 = 6MB
  bf16* wo_bf   = wqkv_bf + 3 * 1048576;          // 2MB
  bf16* tabc    = wo_bf + 1048576;                // 512KB (8192x32 bf16)
  bf16* tabs    = tabc + 262144;                  // 512KB
  bf16* att_bf  = x_bf;   // alias: x_bf dead after QKV projection

  cvt_all<<<7168, 256, 0, stream>>>(x, wq, wk, wv, wo, tp, x_bf, wqkv_bf,
                                    wo_bf, tabc, tabs);

  dim3 gq(64, 24);
  gemm_k<0><<<gq, 256, 0, stream>>>(x_bf, wqkv_bf, tabc, tabs, q_bf, k_bf,
                                    v_bf, nullptr);

  attn_k<<<512, 512, 0, stream>>>(q_bf, k_bf, v_bf, att_bf);

  dim3 go(64, 8);
  gemm_k<2><<<go, 256, 0, stream>>>(att_bf, wo_bf, nullptr, nullptr, nullptr,
                                    nullptr, nullptr, out);
}